// Round 16
// baseline (711.412 us; speedup 1.0000x reference)
//
#include <hip/hip_runtime.h>
#include <hip/hip_bf16.h>

typedef __attribute__((ext_vector_type(8))) short short8;
typedef __attribute__((ext_vector_type(4))) float f32x4;

#define TP 46  // active time steps: 30 strided + 16 dense

// raw barrier + counted vmcnt (T3/T4): never drain vmcnt to 0 in a steady loop
#define SBAR() asm volatile("s_barrier" ::: "memory")
#define VMCNT4() asm volatile("s_waitcnt vmcnt(4)" ::: "memory")
#define VMCNT0() asm volatile("s_waitcnt vmcnt(0)" ::: "memory")

__device__ __forceinline__ unsigned short f2bf(float f) {  // RNE (weights, one-time)
  unsigned int u = __float_as_uint(f);
  u = (u + 0x7fff + ((u >> 16) & 1)) >> 16;
  return (unsigned short)u;
}
__device__ __forceinline__ unsigned short f2bf_fast(float f) {
  return (unsigned short)((__float_as_uint(f) + 0x8000u) >> 16);
}
__device__ __forceinline__ float bf2f(short u) {
  return __uint_as_float((unsigned)(unsigned short)u << 16);
}
__device__ __forceinline__ float fast_rcp(float x) {
#if __has_builtin(__builtin_amdgcn_rcpf)
  return __builtin_amdgcn_rcpf(x);
#else
  return 1.0f / x;
#endif
}
__device__ __forceinline__ float fast_rsq(float x) {
#if __has_builtin(__builtin_amdgcn_rsqf)
  return __builtin_amdgcn_rsqf(x);
#else
  return rsqrtf(x);
#endif
}

__device__ __forceinline__ int act_t(int j) { return j < 30 ? (j << 3) : (210 + j); }

// async 16B/lane global->LDS: lds base must be wave-uniform; HW writes lane i at base+i*16
__device__ __forceinline__ void load_lds16(const unsigned short* g, unsigned short* lds_base) {
#if __has_builtin(__builtin_amdgcn_global_load_lds)
  __builtin_amdgcn_global_load_lds(
      (const __attribute__((address_space(1))) unsigned int*)(unsigned long long)g,
      (__attribute__((address_space(3))) unsigned int*)(unsigned int)(unsigned long long)lds_base,
      16, 0, 0);
#else
  int lane = threadIdx.x & 63;
  *(short8*)(lds_base + lane * 8) = *(const short8*)g;
#endif
}

// ---------------- weight convert to fragment-ordered bf16 ----------------
// pool elems: 128 tiles of 4096 for QKV/O (frag-ordered A-operand for swapped
// mfma):  tiles 0..15 Wq_t, 16..31 Wk_t, 32..47 Wv_t, 48..63 Wo_t,
//         64..79 Wq_s, 80..95 Wk_s, 96..111 Wv_s, 112..127 Wo_s.
// tile off = tile*4096 + ks*512 + lane*8 + e -> w[(ks*32+lg*8+e)*256 + ct*16+lr]
// W1F 524288: ((fc*2+ct)*8+ks)*512+lane*8+e -> w1[(ks*32+lg*8+e)*1024 + fc*32+ct*16+lr]
// W2F 786432: (fc*16+ct2)*512+lane*8+e2     -> w2[(fc*32+lg*8+e2)*256 + ct2*16+lr]
__global__ __launch_bounds__(256) void convw_kernel(
    const float* __restrict__ wq_t, const float* __restrict__ wk_t,
    const float* __restrict__ wv_t, const float* __restrict__ wo_t,
    const float* __restrict__ wq_s, const float* __restrict__ wk_s,
    const float* __restrict__ wv_s, const float* __restrict__ wo_s,
    const float* __restrict__ w1, const float* __restrict__ w2,
    unsigned short* __restrict__ pool) {
  int idx = blockIdx.x * 256 + threadIdx.x;
  float v;
  if (idx < 524288) {
    int tile = idx >> 12, local = idx & 4095;
    int ks = local >> 9, q = local & 511;
    int l = q >> 3, e = q & 7;
    int lr = l & 15, lg = l >> 4;
    int ct = tile & 15, grp = tile >> 4;
    const float* s = (grp == 0) ? wq_t : (grp == 1) ? wk_t : (grp == 2) ? wv_t :
                     (grp == 3) ? wo_t : (grp == 4) ? wq_s : (grp == 5) ? wk_s :
                     (grp == 6) ? wv_s : wo_s;
    v = s[(size_t)(ks * 32 + lg * 8 + e) * 256 + ct * 16 + lr];
  } else if (idx < 786432) {
    int local = idx - 524288;
    int e = local & 7, t = local >> 3;
    int lane = t & 63, ks = (t >> 6) & 7, ct = (t >> 9) & 1, fc = t >> 10;
    int lr = lane & 15, lg = lane >> 4;
    v = w1[(size_t)(ks * 32 + lg * 8 + e) * 1024 + fc * 32 + ct * 16 + lr];
  } else {
    int local = idx - 786432;
    int e2 = local & 7, t = local >> 3;
    int lane = t & 63, ct2 = (t >> 6) & 15, fc = t >> 10;
    int lr = lane & 15, lg = lane >> 4;
    v = w2[(size_t)(fc * 32 + lg * 8 + e2) * 256 + ct2 * 16 + lr];
  }
  pool[idx] = f2bf(v);
}

// ---------------- fused rmsnorm + QKV projection (counted-vmcnt pipeline) ----
// 256 thr / 4 waves / 128 rows. rms in-register. 48 weight tiles consumed as
// 24 rounds of 16KB pairs, double-buffered; 2 raw barriers + vmcnt(4) per
// round (audited ledger: top-of-round outstanding = 4(cur)+4(next), vmcnt(4)
// retires exactly the current pair).
template<int GATHER>
__global__ __launch_bounds__(256) void qkv_kernel(
    const float* __restrict__ src, const float* __restrict__ nw,
    const unsigned short* __restrict__ WF,  // 48 fragment-ordered tiles
    unsigned short* __restrict__ qb, unsigned short* __restrict__ kb,
    unsigned short* __restrict__ vb, int row_base) {
  __shared__ __align__(16) unsigned short Wbuf[2][8192];
  int tid = threadIdx.x, wv = tid >> 6, lane = tid & 63, lr = lane & 15, lg = lane >> 4;
  int row0 = blockIdx.x * 128 + wv * 32;
  short8 afrag[2][8];
  #pragma unroll
  for (int rt = 0; rt < 2; ++rt) {
    int lrow = row0 + rt * 16 + lr;
    const float* rp;
    if (GATHER) {
      int gr = row_base + lrow;
      int b = gr / 11776; int rem = gr - b * 11776;
      int j = rem >> 8, n = rem & 255;
      rp = src + (((size_t)((b << 8) + n) << 8) + act_t(j)) * 256;
    } else {
      rp = src + (size_t)lrow * 256;
    }
    float4 x[16];
    #pragma unroll
    for (int ks = 0; ks < 8; ++ks) {
      x[ks * 2]     = *(const float4*)(rp + ks * 32 + lg * 8);
      x[ks * 2 + 1] = *(const float4*)(rp + ks * 32 + lg * 8 + 4);
    }
    float ss = 0.f;
    #pragma unroll
    for (int i = 0; i < 16; ++i)
      ss += x[i].x * x[i].x + x[i].y * x[i].y + x[i].z * x[i].z + x[i].w * x[i].w;
    ss += __shfl_xor(ss, 16, 64);
    ss += __shfl_xor(ss, 32, 64);
    float sc = fast_rsq(ss * 0.00390625f + 1e-6f);
    #pragma unroll
    for (int ks = 0; ks < 8; ++ks) {
      float4 w0 = *(const float4*)(nw + ks * 32 + lg * 8);
      float4 w1_ = *(const float4*)(nw + ks * 32 + lg * 8 + 4);
      short8 af;
      af[0] = (short)f2bf_fast(x[ks * 2].x * sc * w0.x);
      af[1] = (short)f2bf_fast(x[ks * 2].y * sc * w0.y);
      af[2] = (short)f2bf_fast(x[ks * 2].z * sc * w0.z);
      af[3] = (short)f2bf_fast(x[ks * 2].w * sc * w0.w);
      af[4] = (short)f2bf_fast(x[ks * 2 + 1].x * sc * w1_.x);
      af[5] = (short)f2bf_fast(x[ks * 2 + 1].y * sc * w1_.y);
      af[6] = (short)f2bf_fast(x[ks * 2 + 1].z * sc * w1_.z);
      af[7] = (short)f2bf_fast(x[ks * 2 + 1].w * sc * w1_.w);
      afrag[rt][ks] = af;
    }
  }
  // stage pair 0 (16 x 1KB segments; each wave stages 4)
  #pragma unroll
  for (int i = 0; i < 4; ++i) {
    int s = wv * 4 + i;
    load_lds16(WF + (size_t)s * 512 + lane * 8, &Wbuf[0][s * 512]);
  }
  f32x4 zero = {0.f, 0.f, 0.f, 0.f};
  for (int r = 0; r < 24; ++r) {
    SBAR();  // B1: all waves done computing pair r-1 -> buf[(r+1)&1] reusable
    if (r < 23) {
      #pragma unroll
      for (int i = 0; i < 4; ++i) {
        int s = wv * 4 + i;
        load_lds16(WF + (size_t)(r + 1) * 8192 + s * 512 + lane * 8,
                   &Wbuf[(r + 1) & 1][s * 512]);
      }
      VMCNT4();  // pair r's 4 loads retired; r+1's 4 stay in flight
    } else {
      VMCNT0();
    }
    SBAR();  // B2: every wave has waited its vmcnt -> pair r fully in LDS
    #pragma unroll
    for (int sub = 0; sub < 2; ++sub) {
      int t = r * 2 + sub;
      const unsigned short* Ws = &Wbuf[r & 1][sub * 4096];
      f32x4 a0 = zero, a1 = zero;
      #pragma unroll
      for (int ks = 0; ks < 8; ++ks) {
        short8 bw = *(const short8*)&Ws[ks * 512 + lane * 8];
        a0 = __builtin_amdgcn_mfma_f32_16x16x32_bf16(bw, afrag[0][ks], a0, 0, 0, 0);
        a1 = __builtin_amdgcn_mfma_f32_16x16x32_bf16(bw, afrag[1][ks], a1, 0, 0, 0);
      }
      int m = t >> 4, ct = t & 15;
      unsigned short* dst = (m == 0) ? qb : (m == 1) ? kb : vb;
      ushort4 p0, p1;
      p0.x = f2bf_fast(a0[0]); p0.y = f2bf_fast(a0[1]);
      p0.z = f2bf_fast(a0[2]); p0.w = f2bf_fast(a0[3]);
      p1.x = f2bf_fast(a1[0]); p1.y = f2bf_fast(a1[1]);
      p1.z = f2bf_fast(a1[2]); p1.w = f2bf_fast(a1[3]);
      *(ushort4*)(dst + (size_t)(row0 + lr) * 256 + ct * 16 + lg * 4) = p0;
      *(ushort4*)(dst + (size_t)(row0 + 16 + lr) * 256 + ct * 16 + lg * 4) = p1;
    }
  }
}

// ---------------- output projection GEMM (LDS-staged weights) ----------------
// MODE 1: outf = resid + X@W.  MODE 2: scatter-add into h (float4 RMW).
// 8 rounds of 16KB pairs, __syncthreads (loop body has global resid/outf
// loads whose consumption would force vmcnt(0) anyway).
template<int MODE>
__global__ __launch_bounds__(256) void gemm256_kernel(
    const unsigned short* __restrict__ X, const unsigned short* __restrict__ WF,
    const float* __restrict__ resid, float* __restrict__ outf, int row_base) {
  __shared__ __align__(16) unsigned short Wbuf[2][8192];
  int tid = threadIdx.x, wv = tid >> 6, lane = tid & 63, lr = lane & 15, lg = lane >> 4;
  int row0 = blockIdx.x * 128 + wv * 32;
  short8 afrag[2][8];
  size_t rb[2];
  #pragma unroll
  for (int rt = 0; rt < 2; ++rt) {
    int row = row0 + rt * 16 + lr;
    #pragma unroll
    for (int ks = 0; ks < 8; ++ks)
      afrag[rt][ks] = *(const short8*)(X + (size_t)row * 256 + ks * 32 + lg * 8);
    if (MODE == 1) {
      rb[rt] = (size_t)row * 256;
    } else {
      int gr = row_base + row;
      int b = gr / 11776; int rem = gr - b * 11776;
      int j = rem >> 8, n = rem & 255;
      rb[rt] = (((size_t)((b << 8) + n) << 8) + act_t(j)) * 256;
    }
  }
  #pragma unroll
  for (int i = 0; i < 4; ++i) {
    int s = wv * 4 + i;
    load_lds16(WF + (size_t)s * 512 + lane * 8, &Wbuf[0][s * 512]);
  }
  f32x4 zero = {0.f, 0.f, 0.f, 0.f};
  for (int r = 0; r < 8; ++r) {
    __syncthreads();
    if (r < 7) {
      #pragma unroll
      for (int i = 0; i < 4; ++i) {
        int s = wv * 4 + i;
        load_lds16(WF + (size_t)(r + 1) * 8192 + s * 512 + lane * 8,
                   &Wbuf[(r + 1) & 1][s * 512]);
      }
    }
    __syncthreads();
    #pragma unroll
    for (int sub = 0; sub < 2; ++sub) {
      int t = r * 2 + sub;
      const unsigned short* Ws = &Wbuf[r & 1][sub * 4096];
      f32x4 a0 = zero, a1 = zero;
      #pragma unroll
      for (int ks = 0; ks < 8; ++ks) {
        short8 bw = *(const short8*)&Ws[ks * 512 + lane * 8];
        a0 = __builtin_amdgcn_mfma_f32_16x16x32_bf16(bw, afrag[0][ks], a0, 0, 0, 0);
        a1 = __builtin_amdgcn_mfma_f32_16x16x32_bf16(bw, afrag[1][ks], a1, 0, 0, 0);
      }
      int col = t * 16 + lg * 4;
      if (MODE == 1) {
        float4 r0 = *(const float4*)(resid + rb[0] + col);
        float4 r1 = *(const float4*)(resid + rb[1] + col);
        float4 o0, o1;
        o0.x = r0.x + a0[0]; o0.y = r0.y + a0[1]; o0.z = r0.z + a0[2]; o0.w = r0.w + a0[3];
        o1.x = r1.x + a1[0]; o1.y = r1.y + a1[1]; o1.z = r1.z + a1[2]; o1.w = r1.w + a1[3];
        *(float4*)(outf + rb[0] + col) = o0;
        *(float4*)(outf + rb[1] + col) = o1;
      } else {
        float4 c0 = *(const float4*)(outf + rb[0] + col);
        float4 c1 = *(const float4*)(outf + rb[1] + col);
        c0.x += a0[0]; c0.y += a0[1]; c0.z += a0[2]; c0.w += a0[3];
        c1.x += a1[0]; c1.y += a1[1]; c1.z += a1[2]; c1.w += a1[3];
        *(float4*)(outf + rb[0] + col) = c0;
        *(float4*)(outf + rb[1] + col) = c1;
      }
    }
  }
}

// ---------------- attention: one block per (head, seq); seq len 256, hdim 32 ----------------
// Coalesced staging: lane->(row=tid>>2, chunk=tid&3) => 64B-contiguous reads.
// Swapped QK^T; softmax reduce = 2 shfl_xor; swapped PV; vectorized O store.
// LDS pitches chosen for bank spread: Ksh 42 (21 dw, gcd(21,32)=1 -> conflict-
// free reads), Vtsh/Psh 270 (135 dw, gcd=1 -> conflict-free reads; V-transpose
// write c-groups land on distinct bank sets: 8*270*2/4 % 32 = 24).
template<int MASKED>
__global__ __launch_bounds__(256) void attn_kernel(
    const unsigned short* __restrict__ Q, const unsigned short* __restrict__ K,
    const unsigned short* __restrict__ V, unsigned short* __restrict__ O,
    const int* __restrict__ mask, int seq_base) {
  __shared__ unsigned short Ksh[256][42];    // bank-clean pitch
  __shared__ unsigned short Vtsh[32][270];   // V transposed [d][key]
  __shared__ unsigned short Psh[4][16][270]; // per-wave P: [qrow][key]
  int head = blockIdx.x, seq = blockIdx.y;
  int hc = head * 32;
  size_t sb = (size_t)seq * 65536;
  int tid = threadIdx.x;
  {
    int c = tid & 3, rbase = tid >> 2;
    #pragma unroll
    for (int i = 0; i < 4; ++i) {
      int r = rbase + i * 64;
      *(short8*)&Ksh[r][c * 8] = *(const short8*)(K + sb + (size_t)r * 256 + hc + c * 8);
      short8 vv = *(const short8*)(V + sb + (size_t)r * 256 + hc + c * 8);
      #pragma unroll
      for (int e = 0; e < 8; ++e) Vtsh[c * 8 + e][r] = (unsigned short)vv[e];
    }
  }
  __syncthreads();
  int wv = tid >> 6, lane = tid & 63, lr = lane & 15, lg = lane >> 4;
  const float scale = 0.17677669529663687f;  // 1/sqrt(32)
  int mb = 0;
  if (MASKED) mb = (seq_base + seq) / TP;
  f32x4 zero = {0.f, 0.f, 0.f, 0.f};
  for (int rt = 0; rt < 4; ++rt) {
    int row0 = wv * 64 + rt * 16;
    short8 aq = *(const short8*)(Q + sb + (size_t)(row0 + lr) * 256 + hc + lg * 8);
    f32x4 s[16];
    #pragma unroll
    for (int ct = 0; ct < 16; ++ct) {
      short8 kb = *(const short8*)&Ksh[ct * 16 + lr][lg * 8];
      s[ct] = __builtin_amdgcn_mfma_f32_16x16x32_bf16(kb, aq, zero, 0, 0, 0);
    }
    // s[ct][r] = S[qrow=lr][key = ct*16 + lg*4 + r]
    #pragma unroll
    for (int ct = 0; ct < 16; ++ct) {
      if (MASKED) {
        const int4 m4 = *(const int4*)(mask + mb * 256 + ct * 16 + lg * 4);
        s[ct][0] = m4.x ? s[ct][0] * scale : -1e9f;
        s[ct][1] = m4.y ? s[ct][1] * scale : -1e9f;
        s[ct][2] = m4.z ? s[ct][2] * scale : -1e9f;
        s[ct][3] = m4.w ? s[ct][3] * scale : -1e9f;
      } else {
        #pragma unroll
        for (int r = 0; r < 4; ++r) s[ct][r] *= scale;
      }
    }
    float mx = -3e38f;
    #pragma unroll
    for (int ct = 0; ct < 16; ++ct)
      #pragma unroll
      for (int r = 0; r < 4; ++r) mx = fmaxf(mx, s[ct][r]);
    mx = fmaxf(mx, __shfl_xor(mx, 16, 64));
    mx = fmaxf(mx, __shfl_xor(mx, 32, 64));
    float sum = 0.f;
    #pragma unroll
    for (int ct = 0; ct < 16; ++ct)
      #pragma unroll
      for (int r = 0; r < 4; ++r) {
        float p = __expf(s[ct][r] - mx);
        s[ct][r] = p; sum += p;
      }
    sum += __shfl_xor(sum, 16, 64);
    sum += __shfl_xor(sum, 32, 64);
    float inv = fast_rcp(sum);
    #pragma unroll
    for (int ct = 0; ct < 16; ++ct) {
      ushort4 pk;
      pk.x = f2bf_fast(s[ct][0] * inv); pk.y = f2bf_fast(s[ct][1] * inv);
      pk.z = f2bf_fast(s[ct][2] * inv); pk.w = f2bf_fast(s[ct][3] * inv);
      *(ushort4*)&Psh[wv][lr][ct * 16 + lg * 4] = pk;
    }
    f32x4 o[2] = {zero, zero};
    #pragma unroll
    for (int ks = 0; ks < 8; ++ks) {
      short8 pa = *(const short8*)&Psh[wv][lr][ks * 32 + lg * 8];
      #pragma unroll
      for (int c2 = 0; c2 < 2; ++c2) {
        short8 vbf = *(const short8*)&Vtsh[c2 * 16 + lr][ks * 32 + lg * 8];
        o[c2] = __builtin_amdgcn_mfma_f32_16x16x32_bf16(vbf, pa, o[c2], 0, 0, 0);
      }
    }
    // o[c2][r] = O[qrow=lr][d = c2*16 + lg*4 + r]
    #pragma unroll
    for (int c2 = 0; c2 < 2; ++c2) {
      ushort4 ok;
      ok.x = f2bf_fast(o[c2][0]); ok.y = f2bf_fast(o[c2][1]);
      ok.z = f2bf_fast(o[c2][2]); ok.w = f2bf_fast(o[c2][3]);
      *(ushort4*)(O + sb + (size_t)(row0 + lr) * 256 + hc + c2 * 16 + lg * 4) = ok;
    }
  }
}

// ---------------- fused rms + FFN (R7/R9 known-good): 4 blocks/CU ------------
// 256 thr / 4 waves / 64 rows / 16 rows per wave. Single 32KB weight buffer,
// two barriers per chunk, 37KB LDS. rms prologue keeps x as bf16 (32 VGPRs):
// ss accumulated in fp32 at load, then in-place rescale. oacc 64 AGPR +
// xfrag 32 + temps <= 128 unified -> __launch_bounds__(256,4) = 4 blocks/CU.
__global__ __launch_bounds__(256, 4) void ffn_kernel(
    float* __restrict__ hio, const float* __restrict__ nw,
    const unsigned short* __restrict__ W1F, const unsigned short* __restrict__ W2F,
    const float* __restrict__ b1, const float* __restrict__ b2) {
  __shared__ __align__(16) unsigned short Wbuf[16384];  // W1s 0..8191 | W2s 8192..
  __shared__ __align__(16) unsigned short Psh[4][16][36];
  int tid = threadIdx.x;
  int wv = tid >> 6, lane = tid & 63, lr = lane & 15, lg = lane >> 4;
  int wrow = blockIdx.x * 64 + wv * 16;
  const float* rp = hio + (size_t)(wrow + lr) * 256;
  short8 xfrag[8];
  float ss = 0.f;
  #pragma unroll
  for (int ks = 0; ks < 8; ++ks) {
    float4 a = *(const float4*)(rp + ks * 32 + lg * 8);
    float4 b = *(const float4*)(rp + ks * 32 + lg * 8 + 4);
    ss += a.x * a.x + a.y * a.y + a.z * a.z + a.w * a.w;
    ss += b.x * b.x + b.y * b.y + b.z * b.z + b.w * b.w;
    short8 xf;
    xf[0] = (short)f2bf_fast(a.x); xf[1] = (short)f2bf_fast(a.y);
    xf[2] = (short)f2bf_fast(a.z); xf[3] = (short)f2bf_fast(a.w);
    xf[4] = (short)f2bf_fast(b.x); xf[5] = (short)f2bf_fast(b.y);
    xf[6] = (short)f2bf_fast(b.z); xf[7] = (short)f2bf_fast(b.w);
    xfrag[ks] = xf;
  }
  ss += __shfl_xor(ss, 16, 64);
  ss += __shfl_xor(ss, 32, 64);
  float sc = fast_rsq(ss * 0.00390625f + 1e-6f);
  #pragma unroll
  for (int ks = 0; ks < 8; ++ks) {
    float4 wa = *(const float4*)(nw + ks * 32 + lg * 8);
    float4 wb = *(const float4*)(nw + ks * 32 + lg * 8 + 4);
    short8 xf = xfrag[ks], af;
    af[0] = (short)f2bf_fast(bf2f(xf[0]) * sc * wa.x);
    af[1] = (short)f2bf_fast(bf2f(xf[1]) * sc * wa.y);
    af[2] = (short)f2bf_fast(bf2f(xf[2]) * sc * wa.z);
    af[3] = (short)f2bf_fast(bf2f(xf[3]) * sc * wa.w);
    af[4] = (short)f2bf_fast(bf2f(xf[4]) * sc * wb.x);
    af[5] = (short)f2bf_fast(bf2f(xf[5]) * sc * wb.y);
    af[6] = (short)f2bf_fast(bf2f(xf[6]) * sc * wb.z);
    af[7] = (short)f2bf_fast(bf2f(xf[7]) * sc * wb.w);
    xfrag[ks] = af;
  }
  f32x4 zero = {0.f, 0.f, 0.f, 0.f};
  f32x4 oacc[16];
  #pragma unroll
  for (int ct = 0; ct < 16; ++ct) oacc[ct] = zero;
  for (int fc = 0; fc < 32; ++fc) {
    __syncthreads();  // all waves done reading previous chunk
    #pragma unroll
    for (int i = 0; i < 8; ++i) {
      int s = wv * 8 + i;
      const unsigned short* srcp = (s < 16) ? (W1F + (size_t)fc * 8192 + s * 512)
                                            : (W2F + (size_t)fc * 8192 + (s - 16) * 512);
      load_lds16(srcp + lane * 8, &Wbuf[s * 512]);
    }
    __syncthreads();  // staging complete (vmcnt drain + barrier)
    const unsigned short* W1s = &Wbuf[0];
    const unsigned short* W2s = &Wbuf[8192];
    f32x4 hacc[2];
    hacc[0] = zero; hacc[1] = zero;
    #pragma unroll
    for (int ks = 0; ks < 8; ++ks) {
      #pragma unroll
      for (int ct = 0; ct < 2; ++ct) {
        short8 w1f = *(const short8*)&W1s[(ct * 8 + ks) * 512 + lane * 8];
        // swapped: D[ff][xrow] -> lane holds 4 consecutive ff for xrow=lr
        hacc[ct] = __builtin_amdgcn_mfma_f32_16x16x32_bf16(w1f, xfrag[ks], hacc[ct], 0, 0, 0);
      }
    }
    #pragma unroll
    for (int ct = 0; ct < 2; ++ct) {
      float4 bb = *(const float4*)(b1 + fc * 32 + ct * 16 + lg * 4);
      ushort4 pk;
      float hv = hacc[ct][0] + bb.x;
      pk.x = f2bf_fast(hv * fast_rcp(1.0f + __expf(-1.5957691216057308f * fmaf(0.044715f * hv, hv * hv, hv))));
      hv = hacc[ct][1] + bb.y;
      pk.y = f2bf_fast(hv * fast_rcp(1.0f + __expf(-1.5957691216057308f * fmaf(0.044715f * hv, hv * hv, hv))));
      hv = hacc[ct][2] + bb.z;
      pk.z = f2bf_fast(hv * fast_rcp(1.0f + __expf(-1.5957691216057308f * fmaf(0.044715f * hv, hv * hv, hv))));
      hv = hacc[ct][3] + bb.w;
      pk.w = f2bf_fast(hv * fast_rcp(1.0f + __expf(-1.5957691216057308f * fmaf(0.044715f * hv, hv * hv, hv))));
      *(ushort4*)&Psh[wv][lr][ct * 16 + lg * 4] = pk;  // [xrow=lr][ff]
    }
    short8 pa = *(const short8*)&Psh[wv][lr][lg * 8];
    #pragma unroll
    for (int ct2 = 0; ct2 < 16; ++ct2) {
      short8 bw2 = *(const short8*)&W2s[ct2 * 512 + lane * 8];
      oacc[ct2] = __builtin_amdgcn_mfma_f32_16x16x32_bf16(bw2, pa, oacc[ct2], 0, 0, 0);
    }
  }
  // epilogue: lane holds 4 consecutive out-cols for row = wrow + lr
  size_t rbase = (size_t)(wrow + lr) * 256;
  #pragma unroll
  for (int ct2 = 0; ct2 < 16; ++ct2) {
    int col = ct2 * 16 + lg * 4;
    float4 bb2 = *(const float4*)(b2 + col);
    float4 cur = *(const float4*)(hio + rbase + col);
    cur.x += oacc[ct2][0] + bb2.x;
    cur.y += oacc[ct2][1] + bb2.y;
    cur.z += oacc[ct2][2] + bb2.z;
    cur.w += oacc[ct2][3] + bb2.w;
    *(float4*)(hio + rbase + col) = cur;
  }
}

extern "C" void kernel_launch(void* const* d_in, const int* in_sizes, int n_in,
                              void* d_out, int out_size, void* d_ws, size_t ws_size,
                              hipStream_t stream) {
  (void)in_sizes; (void)n_in; (void)out_size;
  const float* h   = (const float*)d_in[0];
  const int* smask = (const int*)d_in[1];
  const float* ntw = (const float*)d_in[2];
  const float* nsw = (const float*)d_in[3];
  const float* nfw = (const float*)d_in[4];
  const float* wq_t = (const float*)d_in[5];
  const float* wk_t = (const float*)d_in[6];
  const float* wv_t = (const float*)d_in[7];
  const float* wo_t = (const float*)d_in[8];
  const float* wq_s = (const float*)d_in[9];
  const float* wk_s = (const float*)d_in[10];
  const float* wv_s = (const float*)d_in[11];
  const float* wo_s = (const float*)d_in[12];
  const float* w1  = (const float*)d_in[13];
  const float* b1  = (const float*)d_in[14];
  const float* w2  = (const float*)d_in[15];
  const float* b2  = (const float*)d_in[16];
  float* out = (float*)d_out;
  unsigned short* pool = (unsigned short*)d_ws;

  unsigned short* WQKVtF = pool;                 // tiles 0..47
  unsigned short* WOtF   = pool + 196608;        // tiles 48..63
  unsigned short* WQKVsF = pool + 262144;        // tiles 64..111
  unsigned short* WOsF   = pool + 458752;        // tiles 112..127
  unsigned short* W1F    = pool + 524288;
  unsigned short* W2F    = pool + 786432;

  size_t wbytes = 1048576ull * 2;
  size_t avail = (ws_size > wbytes) ? (ws_size - wbytes) : 0;
  long long scl = (long long)(avail / 524288ull);  // 4 buffers x 128KB per sequence
  int SC = scl < 1 ? 1 : (scl > 512 ? 512 : (int)scl);
  unsigned short* xnorm = pool + 1048576;  // attention output buffer
  unsigned short* qb = xnorm + (size_t)SC * 65536;
  unsigned short* kb = qb + (size_t)SC * 65536;
  unsigned short* vb = kb + (size_t)SC * 65536;

  convw_kernel<<<4096, 256, 0, stream>>>(wq_t, wk_t, wv_t, wo_t, wq_s, wk_s, wv_s,
                                         wo_s, w1, w2, pool);

  // ---- stage 1: time attention over (b,n) sequences (512 of them) ----
  for (int s0 = 0; s0 < 512; s0 += SC) {
    int ns = (512 - s0 < SC) ? (512 - s0) : SC;
    int rows = ns * 256;
    qkv_kernel<0><<<rows / 128, 256, 0, stream>>>(h + (size_t)s0 * 65536, ntw, WQKVtF,
                                                  qb, kb, vb, 0);
    attn_kernel<0><<<dim3(8, ns), 256, 0, stream>>>(qb, kb, vb, xnorm, nullptr, 0);
    gemm256_kernel<1><<<rows / 128, 256, 0, stream>>>(xnorm, WOtF,
        h + (size_t)s0 * 65536, out + (size_t)s0 * 65536, 0);
  }

  // ---- stage 2: stock attention over gathered active-t slices (92 sequences) ----
  int SC2 = SC < 92 ? SC : 92;
  for (int s0 = 0; s0 < 92; s0 += SC2) {
    int ns = (92 - s0 < SC2) ? (92 - s0) : SC2;
    int rows = ns * 256;
    qkv_kernel<1><<<rows / 128, 256, 0, stream>>>(out, nsw, WQKVsF, qb, kb, vb, s0 * 256);
    attn_kernel<1><<<dim3(8, ns), 256, 0, stream>>>(qb, kb, vb, xnorm, smask, s0);
    gemm256_kernel<2><<<rows / 128, 256, 0, stream>>>(xnorm, WOsF, nullptr, out, s0 * 256);
  }

  // ---- stage 3: fused rms + FFN (single dispatch, 2048 blocks x 256 threads) ----
  ffn_kernel<<<2048, 256, 0, stream>>>(out, nfw, W1F, W2F, b1, b2);
}

// Round 17
// 698.395 us; speedup vs baseline: 1.0186x; 1.0186x over previous
//
#include <hip/hip_runtime.h>
#include <hip/hip_bf16.h>

typedef __attribute__((ext_vector_type(8))) short short8;
typedef __attribute__((ext_vector_type(4))) float f32x4;

#define TP 46  // active time steps: 30 strided + 16 dense

// raw barrier + counted vmcnt (T3/T4): never drain vmcnt to 0 in a steady loop
#define SBAR() asm volatile("s_barrier" ::: "memory")
#define VMCNT4() asm volatile("s_waitcnt vmcnt(4)" ::: "memory")
#define VMCNT0() asm volatile("s_waitcnt vmcnt(0)" ::: "memory")

__device__ __forceinline__ unsigned short f2bf(float f) {  // RNE (weights, one-time)
  unsigned int u = __float_as_uint(f);
  u = (u + 0x7fff + ((u >> 16) & 1)) >> 16;
  return (unsigned short)u;
}
__device__ __forceinline__ unsigned short f2bf_fast(float f) {
  return (unsigned short)((__float_as_uint(f) + 0x8000u) >> 16);
}
__device__ __forceinline__ float bf2f(short u) {
  return __uint_as_float((unsigned)(unsigned short)u << 16);
}
__device__ __forceinline__ float fast_rcp(float x) {
#if __has_builtin(__builtin_amdgcn_rcpf)
  return __builtin_amdgcn_rcpf(x);
#else
  return 1.0f / x;
#endif
}
__device__ __forceinline__ float fast_rsq(float x) {
#if __has_builtin(__builtin_amdgcn_rsqf)
  return __builtin_amdgcn_rsqf(x);
#else
  return rsqrtf(x);
#endif
}

__device__ __forceinline__ int act_t(int j) { return j < 30 ? (j << 3) : (210 + j); }

// async 16B/lane global->LDS: lds base must be wave-uniform; HW writes lane i at base+i*16
__device__ __forceinline__ void load_lds16(const unsigned short* g, unsigned short* lds_base) {
#if __has_builtin(__builtin_amdgcn_global_load_lds)
  __builtin_amdgcn_global_load_lds(
      (const __attribute__((address_space(1))) unsigned int*)(unsigned long long)g,
      (__attribute__((address_space(3))) unsigned int*)(unsigned int)(unsigned long long)lds_base,
      16, 0, 0);
#else
  int lane = threadIdx.x & 63;
  *(short8*)(lds_base + lane * 8) = *(const short8*)g;
#endif
}

// ---------------- weight convert to fragment-ordered bf16 ----------------
// pool elems: 128 tiles of 4096 for QKV/O (frag-ordered A-operand for swapped
// mfma):  tiles 0..15 Wq_t, 16..31 Wk_t, 32..47 Wv_t, 48..63 Wo_t,
//         64..79 Wq_s, 80..95 Wk_s, 96..111 Wv_s, 112..127 Wo_s.
// tile off = tile*4096 + ks*512 + lane*8 + e -> w[(ks*32+lg*8+e)*256 + ct*16+lr]
// W1F 524288: ((fc*2+ct)*8+ks)*512+lane*8+e -> w1[(ks*32+lg*8+e)*1024 + fc*32+ct*16+lr]
// W2F 786432: (fc*16+ct2)*512+lane*8+e2     -> w2[(fc*32+lg*8+e2)*256 + ct2*16+lr]
__global__ __launch_bounds__(256) void convw_kernel(
    const float* __restrict__ wq_t, const float* __restrict__ wk_t,
    const float* __restrict__ wv_t, const float* __restrict__ wo_t,
    const float* __restrict__ wq_s, const float* __restrict__ wk_s,
    const float* __restrict__ wv_s, const float* __restrict__ wo_s,
    const float* __restrict__ w1, const float* __restrict__ w2,
    unsigned short* __restrict__ pool) {
  int idx = blockIdx.x * 256 + threadIdx.x;
  float v;
  if (idx < 524288) {
    int tile = idx >> 12, local = idx & 4095;
    int ks = local >> 9, q = local & 511;
    int l = q >> 3, e = q & 7;
    int lr = l & 15, lg = l >> 4;
    int ct = tile & 15, grp = tile >> 4;
    const float* s = (grp == 0) ? wq_t : (grp == 1) ? wk_t : (grp == 2) ? wv_t :
                     (grp == 3) ? wo_t : (grp == 4) ? wq_s : (grp == 5) ? wk_s :
                     (grp == 6) ? wv_s : wo_s;
    v = s[(size_t)(ks * 32 + lg * 8 + e) * 256 + ct * 16 + lr];
  } else if (idx < 786432) {
    int local = idx - 524288;
    int e = local & 7, t = local >> 3;
    int lane = t & 63, ks = (t >> 6) & 7, ct = (t >> 9) & 1, fc = t >> 10;
    int lr = lane & 15, lg = lane >> 4;
    v = w1[(size_t)(ks * 32 + lg * 8 + e) * 1024 + fc * 32 + ct * 16 + lr];
  } else {
    int local = idx - 786432;
    int e2 = local & 7, t = local >> 3;
    int lane = t & 63, ct2 = (t >> 6) & 15, fc = t >> 10;
    int lr = lane & 15, lg = lane >> 4;
    v = w2[(size_t)(fc * 32 + lg * 8 + e2) * 256 + ct2 * 16 + lr];
  }
  pool[idx] = f2bf(v);
}

// ---------------- fused rmsnorm + QKV projection (counted-vmcnt pipeline) ----
// 256 thr / 4 waves / 128 rows. rms in-register. 48 weight tiles consumed as
// 24 rounds of 16KB pairs, double-buffered; 2 raw barriers + vmcnt(4) per
// round (audited ledger: top-of-round outstanding = 4(cur)+4(next), vmcnt(4)
// retires exactly the current pair).
template<int GATHER>
__global__ __launch_bounds__(256) void qkv_kernel(
    const float* __restrict__ src, const float* __restrict__ nw,
    const unsigned short* __restrict__ WF,  // 48 fragment-ordered tiles
    unsigned short* __restrict__ qb, unsigned short* __restrict__ kb,
    unsigned short* __restrict__ vb, int row_base) {
  __shared__ __align__(16) unsigned short Wbuf[2][8192];
  int tid = threadIdx.x, wv = tid >> 6, lane = tid & 63, lr = lane & 15, lg = lane >> 4;
  int row0 = blockIdx.x * 128 + wv * 32;
  short8 afrag[2][8];
  #pragma unroll
  for (int rt = 0; rt < 2; ++rt) {
    int lrow = row0 + rt * 16 + lr;
    const float* rp;
    if (GATHER) {
      int gr = row_base + lrow;
      int b = gr / 11776; int rem = gr - b * 11776;
      int j = rem >> 8, n = rem & 255;
      rp = src + (((size_t)((b << 8) + n) << 8) + act_t(j)) * 256;
    } else {
      rp = src + (size_t)lrow * 256;
    }
    float4 x[16];
    #pragma unroll
    for (int ks = 0; ks < 8; ++ks) {
      x[ks * 2]     = *(const float4*)(rp + ks * 32 + lg * 8);
      x[ks * 2 + 1] = *(const float4*)(rp + ks * 32 + lg * 8 + 4);
    }
    float ss = 0.f;
    #pragma unroll
    for (int i = 0; i < 16; ++i)
      ss += x[i].x * x[i].x + x[i].y * x[i].y + x[i].z * x[i].z + x[i].w * x[i].w;
    ss += __shfl_xor(ss, 16, 64);
    ss += __shfl_xor(ss, 32, 64);
    float sc = fast_rsq(ss * 0.00390625f + 1e-6f);
    #pragma unroll
    for (int ks = 0; ks < 8; ++ks) {
      float4 w0 = *(const float4*)(nw + ks * 32 + lg * 8);
      float4 w1_ = *(const float4*)(nw + ks * 32 + lg * 8 + 4);
      short8 af;
      af[0] = (short)f2bf_fast(x[ks * 2].x * sc * w0.x);
      af[1] = (short)f2bf_fast(x[ks * 2].y * sc * w0.y);
      af[2] = (short)f2bf_fast(x[ks * 2].z * sc * w0.z);
      af[3] = (short)f2bf_fast(x[ks * 2].w * sc * w0.w);
      af[4] = (short)f2bf_fast(x[ks * 2 + 1].x * sc * w1_.x);
      af[5] = (short)f2bf_fast(x[ks * 2 + 1].y * sc * w1_.y);
      af[6] = (short)f2bf_fast(x[ks * 2 + 1].z * sc * w1_.z);
      af[7] = (short)f2bf_fast(x[ks * 2 + 1].w * sc * w1_.w);
      afrag[rt][ks] = af;
    }
  }
  // stage pair 0 (16 x 1KB segments; each wave stages 4)
  #pragma unroll
  for (int i = 0; i < 4; ++i) {
    int s = wv * 4 + i;
    load_lds16(WF + (size_t)s * 512 + lane * 8, &Wbuf[0][s * 512]);
  }
  f32x4 zero = {0.f, 0.f, 0.f, 0.f};
  for (int r = 0; r < 24; ++r) {
    SBAR();  // B1: all waves done computing pair r-1 -> buf[(r+1)&1] reusable
    if (r < 23) {
      #pragma unroll
      for (int i = 0; i < 4; ++i) {
        int s = wv * 4 + i;
        load_lds16(WF + (size_t)(r + 1) * 8192 + s * 512 + lane * 8,
                   &Wbuf[(r + 1) & 1][s * 512]);
      }
      VMCNT4();  // pair r's 4 loads retired; r+1's 4 stay in flight
    } else {
      VMCNT0();
    }
    SBAR();  // B2: every wave has waited its vmcnt -> pair r fully in LDS
    #pragma unroll
    for (int sub = 0; sub < 2; ++sub) {
      int t = r * 2 + sub;
      const unsigned short* Ws = &Wbuf[r & 1][sub * 4096];
      f32x4 a0 = zero, a1 = zero;
      #pragma unroll
      for (int ks = 0; ks < 8; ++ks) {
        short8 bw = *(const short8*)&Ws[ks * 512 + lane * 8];
        a0 = __builtin_amdgcn_mfma_f32_16x16x32_bf16(bw, afrag[0][ks], a0, 0, 0, 0);
        a1 = __builtin_amdgcn_mfma_f32_16x16x32_bf16(bw, afrag[1][ks], a1, 0, 0, 0);
      }
      int m = t >> 4, ct = t & 15;
      unsigned short* dst = (m == 0) ? qb : (m == 1) ? kb : vb;
      ushort4 p0, p1;
      p0.x = f2bf_fast(a0[0]); p0.y = f2bf_fast(a0[1]);
      p0.z = f2bf_fast(a0[2]); p0.w = f2bf_fast(a0[3]);
      p1.x = f2bf_fast(a1[0]); p1.y = f2bf_fast(a1[1]);
      p1.z = f2bf_fast(a1[2]); p1.w = f2bf_fast(a1[3]);
      *(ushort4*)(dst + (size_t)(row0 + lr) * 256 + ct * 16 + lg * 4) = p0;
      *(ushort4*)(dst + (size_t)(row0 + 16 + lr) * 256 + ct * 16 + lg * 4) = p1;
    }
  }
}

// ---------------- output projection GEMM (LDS-staged weights) ----------------
// MODE 1: outf = resid + X@W.  MODE 2: scatter-add into h (float4 RMW).
// 8 rounds of 16KB pairs, __syncthreads (loop body has global resid/outf
// loads whose consumption would force vmcnt(0) anyway).
template<int MODE>
__global__ __launch_bounds__(256) void gemm256_kernel(
    const unsigned short* __restrict__ X, const unsigned short* __restrict__ WF,
    const float* __restrict__ resid, float* __restrict__ outf, int row_base) {
  __shared__ __align__(16) unsigned short Wbuf[2][8192];
  int tid = threadIdx.x, wv = tid >> 6, lane = tid & 63, lr = lane & 15, lg = lane >> 4;
  int row0 = blockIdx.x * 128 + wv * 32;
  short8 afrag[2][8];
  size_t rb[2];
  #pragma unroll
  for (int rt = 0; rt < 2; ++rt) {
    int row = row0 + rt * 16 + lr;
    #pragma unroll
    for (int ks = 0; ks < 8; ++ks)
      afrag[rt][ks] = *(const short8*)(X + (size_t)row * 256 + ks * 32 + lg * 8);
    if (MODE == 1) {
      rb[rt] = (size_t)row * 256;
    } else {
      int gr = row_base + row;
      int b = gr / 11776; int rem = gr - b * 11776;
      int j = rem >> 8, n = rem & 255;
      rb[rt] = (((size_t)((b << 8) + n) << 8) + act_t(j)) * 256;
    }
  }
  #pragma unroll
  for (int i = 0; i < 4; ++i) {
    int s = wv * 4 + i;
    load_lds16(WF + (size_t)s * 512 + lane * 8, &Wbuf[0][s * 512]);
  }
  f32x4 zero = {0.f, 0.f, 0.f, 0.f};
  for (int r = 0; r < 8; ++r) {
    __syncthreads();
    if (r < 7) {
      #pragma unroll
      for (int i = 0; i < 4; ++i) {
        int s = wv * 4 + i;
        load_lds16(WF + (size_t)(r + 1) * 8192 + s * 512 + lane * 8,
                   &Wbuf[(r + 1) & 1][s * 512]);
      }
    }
    __syncthreads();
    #pragma unroll
    for (int sub = 0; sub < 2; ++sub) {
      int t = r * 2 + sub;
      const unsigned short* Ws = &Wbuf[r & 1][sub * 4096];
      f32x4 a0 = zero, a1 = zero;
      #pragma unroll
      for (int ks = 0; ks < 8; ++ks) {
        short8 bw = *(const short8*)&Ws[ks * 512 + lane * 8];
        a0 = __builtin_amdgcn_mfma_f32_16x16x32_bf16(bw, afrag[0][ks], a0, 0, 0, 0);
        a1 = __builtin_amdgcn_mfma_f32_16x16x32_bf16(bw, afrag[1][ks], a1, 0, 0, 0);
      }
      int col = t * 16 + lg * 4;
      if (MODE == 1) {
        float4 r0 = *(const float4*)(resid + rb[0] + col);
        float4 r1 = *(const float4*)(resid + rb[1] + col);
        float4 o0, o1;
        o0.x = r0.x + a0[0]; o0.y = r0.y + a0[1]; o0.z = r0.z + a0[2]; o0.w = r0.w + a0[3];
        o1.x = r1.x + a1[0]; o1.y = r1.y + a1[1]; o1.z = r1.z + a1[2]; o1.w = r1.w + a1[3];
        *(float4*)(outf + rb[0] + col) = o0;
        *(float4*)(outf + rb[1] + col) = o1;
      } else {
        float4 c0 = *(const float4*)(outf + rb[0] + col);
        float4 c1 = *(const float4*)(outf + rb[1] + col);
        c0.x += a0[0]; c0.y += a0[1]; c0.z += a0[2]; c0.w += a0[3];
        c1.x += a1[0]; c1.y += a1[1]; c1.z += a1[2]; c1.w += a1[3];
        *(float4*)(outf + rb[0] + col) = c0;
        *(float4*)(outf + rb[1] + col) = c1;
      }
    }
  }
}

// ---------------- attention: one block per (head, seq); seq len 256, hdim 32 ----------------
// Coalesced staging: lane->(row=tid>>2, chunk=tid&3) => 64B-contiguous reads.
// Swapped QK^T; softmax reduce = 2 shfl_xor; swapped PV; vectorized O store.
template<int MASKED>
__global__ __launch_bounds__(256) void attn_kernel(
    const unsigned short* __restrict__ Q, const unsigned short* __restrict__ K,
    const unsigned short* __restrict__ V, unsigned short* __restrict__ O,
    const int* __restrict__ mask, int seq_base) {
  __shared__ unsigned short Ksh[256][40];    // padded
  __shared__ unsigned short Vtsh[32][264];   // V transposed [d][key]
  __shared__ unsigned short Psh[4][16][264]; // per-wave P: [qrow][key]
  int head = blockIdx.x, seq = blockIdx.y;
  int hc = head * 32;
  size_t sb = (size_t)seq * 65536;
  int tid = threadIdx.x;
  {
    int c = tid & 3, rbase = tid >> 2;
    #pragma unroll
    for (int i = 0; i < 4; ++i) {
      int r = rbase + i * 64;
      *(short8*)&Ksh[r][c * 8] = *(const short8*)(K + sb + (size_t)r * 256 + hc + c * 8);
      short8 vv = *(const short8*)(V + sb + (size_t)r * 256 + hc + c * 8);
      #pragma unroll
      for (int e = 0; e < 8; ++e) Vtsh[c * 8 + e][r] = (unsigned short)vv[e];
    }
  }
  __syncthreads();
  int wv = tid >> 6, lane = tid & 63, lr = lane & 15, lg = lane >> 4;
  const float scale = 0.17677669529663687f;  // 1/sqrt(32)
  int mb = 0;
  if (MASKED) mb = (seq_base + seq) / TP;
  f32x4 zero = {0.f, 0.f, 0.f, 0.f};
  for (int rt = 0; rt < 4; ++rt) {
    int row0 = wv * 64 + rt * 16;
    short8 aq = *(const short8*)(Q + sb + (size_t)(row0 + lr) * 256 + hc + lg * 8);
    f32x4 s[16];
    #pragma unroll
    for (int ct = 0; ct < 16; ++ct) {
      short8 kb = *(const short8*)&Ksh[ct * 16 + lr][lg * 8];
      s[ct] = __builtin_amdgcn_mfma_f32_16x16x32_bf16(kb, aq, zero, 0, 0, 0);
    }
    // s[ct][r] = S[qrow=lr][key = ct*16 + lg*4 + r]
    #pragma unroll
    for (int ct = 0; ct < 16; ++ct) {
      if (MASKED) {
        const int4 m4 = *(const int4*)(mask + mb * 256 + ct * 16 + lg * 4);
        s[ct][0] = m4.x ? s[ct][0] * scale : -1e9f;
        s[ct][1] = m4.y ? s[ct][1] * scale : -1e9f;
        s[ct][2] = m4.z ? s[ct][2] * scale : -1e9f;
        s[ct][3] = m4.w ? s[ct][3] * scale : -1e9f;
      } else {
        #pragma unroll
        for (int r = 0; r < 4; ++r) s[ct][r] *= scale;
      }
    }
    float mx = -3e38f;
    #pragma unroll
    for (int ct = 0; ct < 16; ++ct)
      #pragma unroll
      for (int r = 0; r < 4; ++r) mx = fmaxf(mx, s[ct][r]);
    mx = fmaxf(mx, __shfl_xor(mx, 16, 64));
    mx = fmaxf(mx, __shfl_xor(mx, 32, 64));
    float sum = 0.f;
    #pragma unroll
    for (int ct = 0; ct < 16; ++ct)
      #pragma unroll
      for (int r = 0; r < 4; ++r) {
        float p = __expf(s[ct][r] - mx);
        s[ct][r] = p; sum += p;
      }
    sum += __shfl_xor(sum, 16, 64);
    sum += __shfl_xor(sum, 32, 64);
    float inv = fast_rcp(sum);
    #pragma unroll
    for (int ct = 0; ct < 16; ++ct) {
      ushort4 pk;
      pk.x = f2bf_fast(s[ct][0] * inv); pk.y = f2bf_fast(s[ct][1] * inv);
      pk.z = f2bf_fast(s[ct][2] * inv); pk.w = f2bf_fast(s[ct][3] * inv);
      *(ushort4*)&Psh[wv][lr][ct * 16 + lg * 4] = pk;
    }
    f32x4 o[2] = {zero, zero};
    #pragma unroll
    for (int ks = 0; ks < 8; ++ks) {
      short8 pa = *(const short8*)&Psh[wv][lr][ks * 32 + lg * 8];
      #pragma unroll
      for (int c2 = 0; c2 < 2; ++c2) {
        short8 vbf = *(const short8*)&Vtsh[c2 * 16 + lr][ks * 32 + lg * 8];
        o[c2] = __builtin_amdgcn_mfma_f32_16x16x32_bf16(vbf, pa, o[c2], 0, 0, 0);
      }
    }
    // o[c2][r] = O[qrow=lr][d = c2*16 + lg*4 + r]
    #pragma unroll
    for (int c2 = 0; c2 < 2; ++c2) {
      ushort4 ok;
      ok.x = f2bf_fast(o[c2][0]); ok.y = f2bf_fast(o[c2][1]);
      ok.z = f2bf_fast(o[c2][2]); ok.w = f2bf_fast(o[c2][3]);
      *(ushort4*)(O + sb + (size_t)(row0 + lr) * 256 + hc + c2 * 16 + lg * 4) = ok;
    }
  }
}

// ---------------- fused rms + FFN (known-good): 4 blocks/CU ------------------
// 256 thr / 4 waves / 64 rows / 16 rows per wave. Single 32KB weight buffer,
// two barriers per chunk, 37KB LDS. rms prologue keeps x as bf16 (32 VGPRs):
// ss accumulated in fp32 at load, then in-place rescale. oacc 64 AGPR +
// xfrag 32 + temps <= 128 unified -> __launch_bounds__(256,4) = 4 blocks/CU.
__global__ __launch_bounds__(256, 4) void ffn_kernel(
    float* __restrict__ hio, const float* __restrict__ nw,
    const unsigned short* __restrict__ W1F, const unsigned short* __restrict__ W2F,
    const float* __restrict__ b1, const float* __restrict__ b2) {
  __shared__ __align__(16) unsigned short Wbuf[16384];  // W1s 0..8191 | W2s 8192..
  __shared__ __align__(16) unsigned short Psh[4][16][36];
  int tid = threadIdx.x;
  int wv = tid >> 6, lane = tid & 63, lr = lane & 15, lg = lane >> 4;
  int wrow = blockIdx.x * 64 + wv * 16;
  const float* rp = hio + (size_t)(wrow + lr) * 256;
  short8 xfrag[8];
  float ss = 0.f;
  #pragma unroll
  for (int ks = 0; ks < 8; ++ks) {
    float4 a = *(const float4*)(rp + ks * 32 + lg * 8);
    float4 b = *(const float4*)(rp + ks * 32 + lg * 8 + 4);
    ss += a.x * a.x + a.y * a.y + a.z * a.z + a.w * a.w;
    ss += b.x * b.x + b.y * b.y + b.z * b.z + b.w * b.w;
    short8 xf;
    xf[0] = (short)f2bf_fast(a.x); xf[1] = (short)f2bf_fast(a.y);
    xf[2] = (short)f2bf_fast(a.z); xf[3] = (short)f2bf_fast(a.w);
    xf[4] = (short)f2bf_fast(b.x); xf[5] = (short)f2bf_fast(b.y);
    xf[6] = (short)f2bf_fast(b.z); xf[7] = (short)f2bf_fast(b.w);
    xfrag[ks] = xf;
  }
  ss += __shfl_xor(ss, 16, 64);
  ss += __shfl_xor(ss, 32, 64);
  float sc = fast_rsq(ss * 0.00390625f + 1e-6f);
  #pragma unroll
  for (int ks = 0; ks < 8; ++ks) {
    float4 wa = *(const float4*)(nw + ks * 32 + lg * 8);
    float4 wb = *(const float4*)(nw + ks * 32 + lg * 8 + 4);
    short8 xf = xfrag[ks], af;
    af[0] = (short)f2bf_fast(bf2f(xf[0]) * sc * wa.x);
    af[1] = (short)f2bf_fast(bf2f(xf[1]) * sc * wa.y);
    af[2] = (short)f2bf_fast(bf2f(xf[2]) * sc * wa.z);
    af[3] = (short)f2bf_fast(bf2f(xf[3]) * sc * wa.w);
    af[4] = (short)f2bf_fast(bf2f(xf[4]) * sc * wb.x);
    af[5] = (short)f2bf_fast(bf2f(xf[5]) * sc * wb.y);
    af[6] = (short)f2bf_fast(bf2f(xf[6]) * sc * wb.z);
    af[7] = (short)f2bf_fast(bf2f(xf[7]) * sc * wb.w);
    xfrag[ks] = af;
  }
  f32x4 zero = {0.f, 0.f, 0.f, 0.f};
  f32x4 oacc[16];
  #pragma unroll
  for (int ct = 0; ct < 16; ++ct) oacc[ct] = zero;
  for (int fc = 0; fc < 32; ++fc) {
    __syncthreads();  // all waves done reading previous chunk
    #pragma unroll
    for (int i = 0; i < 8; ++i) {
      int s = wv * 8 + i;
      const unsigned short* srcp = (s < 16) ? (W1F + (size_t)fc * 8192 + s * 512)
                                            : (W2F + (size_t)fc * 8192 + (s - 16) * 512);
      load_lds16(srcp + lane * 8, &Wbuf[s * 512]);
    }
    __syncthreads();  // staging complete (vmcnt drain + barrier)
    const unsigned short* W1s = &Wbuf[0];
    const unsigned short* W2s = &Wbuf[8192];
    f32x4 hacc[2];
    hacc[0] = zero; hacc[1] = zero;
    #pragma unroll
    for (int ks = 0; ks < 8; ++ks) {
      #pragma unroll
      for (int ct = 0; ct < 2; ++ct) {
        short8 w1f = *(const short8*)&W1s[(ct * 8 + ks) * 512 + lane * 8];
        // swapped: D[ff][xrow] -> lane holds 4 consecutive ff for xrow=lr
        hacc[ct] = __builtin_amdgcn_mfma_f32_16x16x32_bf16(w1f, xfrag[ks], hacc[ct], 0, 0, 0);
      }
    }
    #pragma unroll
    for (int ct = 0; ct < 2; ++ct) {
      float4 bb = *(const float4*)(b1 + fc * 32 + ct * 16 + lg * 4);
      ushort4 pk;
      float hv = hacc[ct][0] + bb.x;
      pk.x = f2bf_fast(hv * fast_rcp(1.0f + __expf(-1.5957691216057308f * fmaf(0.044715f * hv, hv * hv, hv))));
      hv = hacc[ct][1] + bb.y;
      pk.y = f2bf_fast(hv * fast_rcp(1.0f + __expf(-1.5957691216057308f * fmaf(0.044715f * hv, hv * hv, hv))));
      hv = hacc[ct][2] + bb.z;
      pk.z = f2bf_fast(hv * fast_rcp(1.0f + __expf(-1.5957691216057308f * fmaf(0.044715f * hv, hv * hv, hv))));
      hv = hacc[ct][3] + bb.w;
      pk.w = f2bf_fast(hv * fast_rcp(1.0f + __expf(-1.5957691216057308f * fmaf(0.044715f * hv, hv * hv, hv))));
      *(ushort4*)&Psh[wv][lr][ct * 16 + lg * 4] = pk;  // [xrow=lr][ff]
    }
    short8 pa = *(const short8*)&Psh[wv][lr][lg * 8];
    #pragma unroll
    for (int ct2 = 0; ct2 < 16; ++ct2) {
      short8 bw2 = *(const short8*)&W2s[ct2 * 512 + lane * 8];
      oacc[ct2] = __builtin_amdgcn_mfma_f32_16x16x32_bf16(bw2, pa, oacc[ct2], 0, 0, 0);
    }
  }
  // epilogue: lane holds 4 consecutive out-cols for row = wrow + lr
  size_t rbase = (size_t)(wrow + lr) * 256;
  #pragma unroll
  for (int ct2 = 0; ct2 < 16; ++ct2) {
    int col = ct2 * 16 + lg * 4;
    float4 bb2 = *(const float4*)(b2 + col);
    float4 cur = *(const float4*)(hio + rbase + col);
    cur.x += oacc[ct2][0] + bb2.x;
    cur.y += oacc[ct2][1] + bb2.y;
    cur.z += oacc[ct2][2] + bb2.z;
    cur.w += oacc[ct2][3] + bb2.w;
    *(float4*)(hio + rbase + col) = cur;
  }
}

extern "C" void kernel_launch(void* const* d_in, const int* in_sizes, int n_in,
                              void* d_out, int out_size, void* d_ws, size_t ws_size,
                              hipStream_t stream) {
  (void)in_sizes; (void)n_in; (void)out_size;
  const float* h   = (const float*)d_in[0];
  const int* smask = (const int*)d_in[1];
  const float* ntw = (const float*)d_in[2];
  const float* nsw = (const float*)d_in[3];
  const float* nfw = (const float*)d_in[4];
  const float* wq_t = (const float*)d_in[5];
  const float* wk_t = (const float*)d_in[6];
  const float* wv_t = (const float*)d_in[7];
  const float* wo_t = (const float*)d_in[8];
  const float* wq_s = (const float*)d_in[9];
  const float* wk_s = (const float*)d_in[10];
  const float* wv_s = (const float*)d_in[11];
  const float* wo_s = (const float*)d_in[12];
  const float* w1  = (const float*)d_in[13];
  const float* b1  = (const float*)d_in[14];
  const float* w2  = (const float*)d_in[15];
  const float* b2  = (const float*)d_in[16];
  float* out = (float*)d_out;
  unsigned short* pool = (unsigned short*)d_ws;

  unsigned short* WQKVtF = pool;                 // tiles 0..47
  unsigned short* WOtF   = pool + 196608;        // tiles 48..63
  unsigned short* WQKVsF = pool + 262144;        // tiles 64..111
  unsigned short* WOsF   = pool + 458752;        // tiles 112..127
  unsigned short* W1F    = pool + 524288;
  unsigned short* W2F    = pool + 786432;

  size_t wbytes = 1048576ull * 2;
  size_t avail = (ws_size > wbytes) ? (ws_size - wbytes) : 0;
  long long scl = (long long)(avail / 524288ull);  // 4 buffers x 128KB per sequence
  int SC = scl < 1 ? 1 : (scl > 512 ? 512 : (int)scl);
  unsigned short* xnorm = pool + 1048576;  // attention output buffer
  unsigned short* qb = xnorm + (size_t)SC * 65536;
  unsigned short* kb = qb + (size_t)SC * 65536;
  unsigned short* vb = kb + (size_t)SC * 65536;

  convw_kernel<<<4096, 256, 0, stream>>>(wq_t, wk_t, wv_t, wo_t, wq_s, wk_s, wv_s,
                                         wo_s, w1, w2, pool);

  // ---- stage 1: time attention over (b,n) sequences (512 of them) ----
  for (int s0 = 0; s0 < 512; s0 += SC) {
    int ns = (512 - s0 < SC) ? (512 - s0) : SC;
    int rows = ns * 256;
    qkv_kernel<0><<<rows / 128, 256, 0, stream>>>(h + (size_t)s0 * 65536, ntw, WQKVtF,
                                                  qb, kb, vb, 0);
    attn_kernel<0><<<dim3(8, ns), 256, 0, stream>>>(qb, kb, vb, xnorm, nullptr, 0);
    gemm256_kernel<1><<<rows / 128, 256, 0, stream>>>(xnorm, WOtF,
        h + (size_t)s0 * 65536, out + (size_t)s0 * 65536, 0);
  }

  // ---- stage 2: stock attention over gathered active-t slices (92 sequences) ----
  int SC2 = SC < 92 ? SC : 92;
  for (int s0 = 0; s0 < 92; s0 += SC2) {
    int ns = (92 - s0 < SC2) ? (92 - s0) : SC2;
    int rows = ns * 256;
    qkv_kernel<1><<<rows / 128, 256, 0, stream>>>(out, nsw, WQKVsF, qb, kb, vb, s0 * 256);
    attn_kernel<1><<<dim3(8, ns), 256, 0, stream>>>(qb, kb, vb, xnorm, smask, s0);
    gemm256_kernel<2><<<rows / 128, 256, 0, stream>>>(xnorm, WOsF, nullptr, out, s0 * 256);
  }

  // ---- stage 3: fused rms + FFN (single dispatch, 2048 blocks x 256 threads) ----
  ffn_kernel<<<2048, 256, 0, stream>>>(out, nfw, W1F, W2F, b1, b2);
}

// Round 18
// 635.330 us; speedup vs baseline: 1.1198x; 1.0993x over previous
//
#include <hip/hip_runtime.h>
#include <hip/hip_bf16.h>

typedef __attribute__((ext_vector_type(8))) short short8;
typedef __attribute__((ext_vector_type(4))) float f32x4;

#define TP 46  // active time steps: 30 strided + 16 dense

// raw barrier + counted vmcnt (T3/T4): never drain vmcnt to 0 in a steady loop
#define SBAR() asm volatile("s_barrier" ::: "memory")
#define VMCNT4() asm volatile("s_waitcnt vmcnt(4)" ::: "memory")
#define VMCNT0() asm volatile("s_waitcnt vmcnt(0)" ::: "memory")

__device__ __forceinline__ unsigned short f2bf(float f) {  // RNE (weights, one-time)
  unsigned int u = __float_as_uint(f);
  u = (u + 0x7fff + ((u >> 16) & 1)) >> 16;
  return (unsigned short)u;
}
__device__ __forceinline__ unsigned short f2bf_fast(float f) {
  return (unsigned short)((__float_as_uint(f) + 0x8000u) >> 16);
}
__device__ __forceinline__ float bf2f(short u) {
  return __uint_as_float((unsigned)(unsigned short)u << 16);
}
__device__ __forceinline__ float fast_rcp(float x) {
#if __has_builtin(__builtin_amdgcn_rcpf)
  return __builtin_amdgcn_rcpf(x);
#else
  return 1.0f / x;
#endif
}
__device__ __forceinline__ float fast_rsq(float x) {
#if __has_builtin(__builtin_amdgcn_rsqf)
  return __builtin_amdgcn_rsqf(x);
#else
  return rsqrtf(x);
#endif
}

__device__ __forceinline__ int act_t(int j) { return j < 30 ? (j << 3) : (210 + j); }

// async 16B/lane global->LDS: lds base must be wave-uniform; HW writes lane i at base+i*16
__device__ __forceinline__ void load_lds16(const unsigned short* g, unsigned short* lds_base) {
#if __has_builtin(__builtin_amdgcn_global_load_lds)
  __builtin_amdgcn_global_load_lds(
      (const __attribute__((address_space(1))) unsigned int*)(unsigned long long)g,
      (__attribute__((address_space(3))) unsigned int*)(unsigned int)(unsigned long long)lds_base,
      16, 0, 0);
#else
  int lane = threadIdx.x & 63;
  *(short8*)(lds_base + lane * 8) = *(const short8*)g;
#endif
}

// ---------------- weight convert to fragment-ordered bf16 ----------------
// pool elems: 128 tiles of 4096 for QKV/O (frag-ordered A-operand for swapped
// mfma):  tiles 0..15 Wq_t, 16..31 Wk_t, 32..47 Wv_t, 48..63 Wo_t,
//         64..79 Wq_s, 80..95 Wk_s, 96..111 Wv_s, 112..127 Wo_s.
// tile off = tile*4096 + ks*512 + lane*8 + e -> w[(ks*32+lg*8+e)*256 + ct*16+lr]
// W1F 524288: ((fc*2+ct)*8+ks)*512+lane*8+e -> w1[(ks*32+lg*8+e)*1024 + fc*32+ct*16+lr]
// W2F 786432: (fc*16+ct2)*512+lane*8+e2     -> w2[(fc*32+lg*8+e2)*256 + ct2*16+lr]
__global__ __launch_bounds__(256) void convw_kernel(
    const float* __restrict__ wq_t, const float* __restrict__ wk_t,
    const float* __restrict__ wv_t, const float* __restrict__ wo_t,
    const float* __restrict__ wq_s, const float* __restrict__ wk_s,
    const float* __restrict__ wv_s, const float* __restrict__ wo_s,
    const float* __restrict__ w1, const float* __restrict__ w2,
    unsigned short* __restrict__ pool) {
  int idx = blockIdx.x * 256 + threadIdx.x;
  float v;
  if (idx < 524288) {
    int tile = idx >> 12, local = idx & 4095;
    int ks = local >> 9, q = local & 511;
    int l = q >> 3, e = q & 7;
    int lr = l & 15, lg = l >> 4;
    int ct = tile & 15, grp = tile >> 4;
    const float* s = (grp == 0) ? wq_t : (grp == 1) ? wk_t : (grp == 2) ? wv_t :
                     (grp == 3) ? wo_t : (grp == 4) ? wq_s : (grp == 5) ? wk_s :
                     (grp == 6) ? wv_s : wo_s;
    v = s[(size_t)(ks * 32 + lg * 8 + e) * 256 + ct * 16 + lr];
  } else if (idx < 786432) {
    int local = idx - 524288;
    int e = local & 7, t = local >> 3;
    int lane = t & 63, ks = (t >> 6) & 7, ct = (t >> 9) & 1, fc = t >> 10;
    int lr = lane & 15, lg = lane >> 4;
    v = w1[(size_t)(ks * 32 + lg * 8 + e) * 1024 + fc * 32 + ct * 16 + lr];
  } else {
    int local = idx - 786432;
    int e2 = local & 7, t = local >> 3;
    int lane = t & 63, ct2 = (t >> 6) & 15, fc = t >> 10;
    int lr = lane & 15, lg = lane >> 4;
    v = w2[(size_t)(fc * 32 + lg * 8 + e2) * 256 + ct2 * 16 + lr];
  }
  pool[idx] = f2bf(v);
}

// ---------------- fused rmsnorm + QKV projection (counted-vmcnt pipeline) ----
// 256 thr / 4 waves / 128 rows. rms in-register. 48 weight tiles consumed as
// 24 rounds of 16KB pairs, double-buffered; 2 raw barriers + vmcnt(4) per
// round (audited ledger: top-of-round outstanding = 4(cur)+4(next), vmcnt(4)
// retires exactly the current pair).
template<int GATHER>
__global__ __launch_bounds__(256) void qkv_kernel(
    const float* __restrict__ src, const float* __restrict__ nw,
    const unsigned short* __restrict__ WF,  // 48 fragment-ordered tiles
    unsigned short* __restrict__ qb, unsigned short* __restrict__ kb,
    unsigned short* __restrict__ vb, int row_base) {
  __shared__ __align__(16) unsigned short Wbuf[2][8192];
  int tid = threadIdx.x, wv = tid >> 6, lane = tid & 63, lr = lane & 15, lg = lane >> 4;
  int row0 = blockIdx.x * 128 + wv * 32;
  short8 afrag[2][8];
  #pragma unroll
  for (int rt = 0; rt < 2; ++rt) {
    int lrow = row0 + rt * 16 + lr;
    const float* rp;
    if (GATHER) {
      int gr = row_base + lrow;
      int b = gr / 11776; int rem = gr - b * 11776;
      int j = rem >> 8, n = rem & 255;
      rp = src + (((size_t)((b << 8) + n) << 8) + act_t(j)) * 256;
    } else {
      rp = src + (size_t)lrow * 256;
    }
    float4 x[16];
    #pragma unroll
    for (int ks = 0; ks < 8; ++ks) {
      x[ks * 2]     = *(const float4*)(rp + ks * 32 + lg * 8);
      x[ks * 2 + 1] = *(const float4*)(rp + ks * 32 + lg * 8 + 4);
    }
    float ss = 0.f;
    #pragma unroll
    for (int i = 0; i < 16; ++i)
      ss += x[i].x * x[i].x + x[i].y * x[i].y + x[i].z * x[i].z + x[i].w * x[i].w;
    ss += __shfl_xor(ss, 16, 64);
    ss += __shfl_xor(ss, 32, 64);
    float sc = fast_rsq(ss * 0.00390625f + 1e-6f);
    #pragma unroll
    for (int ks = 0; ks < 8; ++ks) {
      float4 w0 = *(const float4*)(nw + ks * 32 + lg * 8);
      float4 w1_ = *(const float4*)(nw + ks * 32 + lg * 8 + 4);
      short8 af;
      af[0] = (short)f2bf_fast(x[ks * 2].x * sc * w0.x);
      af[1] = (short)f2bf_fast(x[ks * 2].y * sc * w0.y);
      af[2] = (short)f2bf_fast(x[ks * 2].z * sc * w0.z);
      af[3] = (short)f2bf_fast(x[ks * 2].w * sc * w0.w);
      af[4] = (short)f2bf_fast(x[ks * 2 + 1].x * sc * w1_.x);
      af[5] = (short)f2bf_fast(x[ks * 2 + 1].y * sc * w1_.y);
      af[6] = (short)f2bf_fast(x[ks * 2 + 1].z * sc * w1_.z);
      af[7] = (short)f2bf_fast(x[ks * 2 + 1].w * sc * w1_.w);
      afrag[rt][ks] = af;
    }
  }
  // stage pair 0 (16 x 1KB segments; each wave stages 4)
  #pragma unroll
  for (int i = 0; i < 4; ++i) {
    int s = wv * 4 + i;
    load_lds16(WF + (size_t)s * 512 + lane * 8, &Wbuf[0][s * 512]);
  }
  f32x4 zero = {0.f, 0.f, 0.f, 0.f};
  for (int r = 0; r < 24; ++r) {
    SBAR();  // B1: all waves done computing pair r-1 -> buf[(r+1)&1] reusable
    if (r < 23) {
      #pragma unroll
      for (int i = 0; i < 4; ++i) {
        int s = wv * 4 + i;
        load_lds16(WF + (size_t)(r + 1) * 8192 + s * 512 + lane * 8,
                   &Wbuf[(r + 1) & 1][s * 512]);
      }
      VMCNT4();  // pair r's 4 loads retired; r+1's 4 stay in flight
    } else {
      VMCNT0();
    }
    SBAR();  // B2: every wave has waited its vmcnt -> pair r fully in LDS
    #pragma unroll
    for (int sub = 0; sub < 2; ++sub) {
      int t = r * 2 + sub;
      const unsigned short* Ws = &Wbuf[r & 1][sub * 4096];
      f32x4 a0 = zero, a1 = zero;
      #pragma unroll
      for (int ks = 0; ks < 8; ++ks) {
        short8 bw = *(const short8*)&Ws[ks * 512 + lane * 8];
        a0 = __builtin_amdgcn_mfma_f32_16x16x32_bf16(bw, afrag[0][ks], a0, 0, 0, 0);
        a1 = __builtin_amdgcn_mfma_f32_16x16x32_bf16(bw, afrag[1][ks], a1, 0, 0, 0);
      }
      int m = t >> 4, ct = t & 15;
      unsigned short* dst = (m == 0) ? qb : (m == 1) ? kb : vb;
      ushort4 p0, p1;
      p0.x = f2bf_fast(a0[0]); p0.y = f2bf_fast(a0[1]);
      p0.z = f2bf_fast(a0[2]); p0.w = f2bf_fast(a0[3]);
      p1.x = f2bf_fast(a1[0]); p1.y = f2bf_fast(a1[1]);
      p1.z = f2bf_fast(a1[2]); p1.w = f2bf_fast(a1[3]);
      *(ushort4*)(dst + (size_t)(row0 + lr) * 256 + ct * 16 + lg * 4) = p0;
      *(ushort4*)(dst + (size_t)(row0 + 16 + lr) * 256 + ct * 16 + lg * 4) = p1;
    }
  }
}

// ---------------- output projection GEMM (LDS-staged weights) ----------------
// MODE 1: outf = resid + X@W.  MODE 2: scatter-add into h (float4 RMW).
// 8 rounds of 16KB pairs, __syncthreads (loop body has global resid/outf
// loads whose consumption would force vmcnt(0) anyway).
template<int MODE>
__global__ __launch_bounds__(256) void gemm256_kernel(
    const unsigned short* __restrict__ X, const unsigned short* __restrict__ WF,
    const float* __restrict__ resid, float* __restrict__ outf, int row_base) {
  __shared__ __align__(16) unsigned short Wbuf[2][8192];
  int tid = threadIdx.x, wv = tid >> 6, lane = tid & 63, lr = lane & 15, lg = lane >> 4;
  int row0 = blockIdx.x * 128 + wv * 32;
  short8 afrag[2][8];
  size_t rb[2];
  #pragma unroll
  for (int rt = 0; rt < 2; ++rt) {
    int row = row0 + rt * 16 + lr;
    #pragma unroll
    for (int ks = 0; ks < 8; ++ks)
      afrag[rt][ks] = *(const short8*)(X + (size_t)row * 256 + ks * 32 + lg * 8);
    if (MODE == 1) {
      rb[rt] = (size_t)row * 256;
    } else {
      int gr = row_base + row;
      int b = gr / 11776; int rem = gr - b * 11776;
      int j = rem >> 8, n = rem & 255;
      rb[rt] = (((size_t)((b << 8) + n) << 8) + act_t(j)) * 256;
    }
  }
  #pragma unroll
  for (int i = 0; i < 4; ++i) {
    int s = wv * 4 + i;
    load_lds16(WF + (size_t)s * 512 + lane * 8, &Wbuf[0][s * 512]);
  }
  f32x4 zero = {0.f, 0.f, 0.f, 0.f};
  for (int r = 0; r < 8; ++r) {
    __syncthreads();
    if (r < 7) {
      #pragma unroll
      for (int i = 0; i < 4; ++i) {
        int s = wv * 4 + i;
        load_lds16(WF + (size_t)(r + 1) * 8192 + s * 512 + lane * 8,
                   &Wbuf[(r + 1) & 1][s * 512]);
      }
    }
    __syncthreads();
    #pragma unroll
    for (int sub = 0; sub < 2; ++sub) {
      int t = r * 2 + sub;
      const unsigned short* Ws = &Wbuf[r & 1][sub * 4096];
      f32x4 a0 = zero, a1 = zero;
      #pragma unroll
      for (int ks = 0; ks < 8; ++ks) {
        short8 bw = *(const short8*)&Ws[ks * 512 + lane * 8];
        a0 = __builtin_amdgcn_mfma_f32_16x16x32_bf16(bw, afrag[0][ks], a0, 0, 0, 0);
        a1 = __builtin_amdgcn_mfma_f32_16x16x32_bf16(bw, afrag[1][ks], a1, 0, 0, 0);
      }
      int col = t * 16 + lg * 4;
      if (MODE == 1) {
        float4 r0 = *(const float4*)(resid + rb[0] + col);
        float4 r1 = *(const float4*)(resid + rb[1] + col);
        float4 o0, o1;
        o0.x = r0.x + a0[0]; o0.y = r0.y + a0[1]; o0.z = r0.z + a0[2]; o0.w = r0.w + a0[3];
        o1.x = r1.x + a1[0]; o1.y = r1.y + a1[1]; o1.z = r1.z + a1[2]; o1.w = r1.w + a1[3];
        *(float4*)(outf + rb[0] + col) = o0;
        *(float4*)(outf + rb[1] + col) = o1;
      } else {
        float4 c0 = *(const float4*)(outf + rb[0] + col);
        float4 c1 = *(const float4*)(outf + rb[1] + col);
        c0.x += a0[0]; c0.y += a0[1]; c0.z += a0[2]; c0.w += a0[3];
        c1.x += a1[0]; c1.y += a1[1]; c1.z += a1[2]; c1.w += a1[3];
        *(float4*)(outf + rb[0] + col) = c0;
        *(float4*)(outf + rb[1] + col) = c1;
      }
    }
  }
}

// ---------------- attention: one block per (head, seq); seq len 256, hdim 32 ----------------
// Coalesced staging: lane->(row=tid>>2, chunk=tid&3) => 64B-contiguous reads.
// Swapped QK^T; softmax reduce = 2 shfl_xor; swapped PV; vectorized O store.
// T5: setprio(1) around the MFMA clusters — attn waves free-run at different
// phases (m191 regime), so priority keeps the matrix pipe fed.
template<int MASKED>
__global__ __launch_bounds__(256) void attn_kernel(
    const unsigned short* __restrict__ Q, const unsigned short* __restrict__ K,
    const unsigned short* __restrict__ V, unsigned short* __restrict__ O,
    const int* __restrict__ mask, int seq_base) {
  __shared__ unsigned short Ksh[256][40];    // padded
  __shared__ unsigned short Vtsh[32][264];   // V transposed [d][key]
  __shared__ unsigned short Psh[4][16][264]; // per-wave P: [qrow][key]
  int head = blockIdx.x, seq = blockIdx.y;
  int hc = head * 32;
  size_t sb = (size_t)seq * 65536;
  int tid = threadIdx.x;
  {
    int c = tid & 3, rbase = tid >> 2;
    #pragma unroll
    for (int i = 0; i < 4; ++i) {
      int r = rbase + i * 64;
      *(short8*)&Ksh[r][c * 8] = *(const short8*)(K + sb + (size_t)r * 256 + hc + c * 8);
      short8 vv = *(const short8*)(V + sb + (size_t)r * 256 + hc + c * 8);
      #pragma unroll
      for (int e = 0; e < 8; ++e) Vtsh[c * 8 + e][r] = (unsigned short)vv[e];
    }
  }
  __syncthreads();
  int wv = tid >> 6, lane = tid & 63, lr = lane & 15, lg = lane >> 4;
  const float scale = 0.17677669529663687f;  // 1/sqrt(32)
  int mb = 0;
  if (MASKED) mb = (seq_base + seq) / TP;
  f32x4 zero = {0.f, 0.f, 0.f, 0.f};
  for (int rt = 0; rt < 4; ++rt) {
    int row0 = wv * 64 + rt * 16;
    short8 aq = *(const short8*)(Q + sb + (size_t)(row0 + lr) * 256 + hc + lg * 8);
    f32x4 s[16];
    __builtin_amdgcn_s_setprio(1);
    #pragma unroll
    for (int ct = 0; ct < 16; ++ct) {
      short8 kb = *(const short8*)&Ksh[ct * 16 + lr][lg * 8];
      s[ct] = __builtin_amdgcn_mfma_f32_16x16x32_bf16(kb, aq, zero, 0, 0, 0);
    }
    __builtin_amdgcn_s_setprio(0);
    // s[ct][r] = S[qrow=lr][key = ct*16 + lg*4 + r]
    #pragma unroll
    for (int ct = 0; ct < 16; ++ct) {
      if (MASKED) {
        const int4 m4 = *(const int4*)(mask + mb * 256 + ct * 16 + lg * 4);
        s[ct][0] = m4.x ? s[ct][0] * scale : -1e9f;
        s[ct][1] = m4.y ? s[ct][1] * scale : -1e9f;
        s[ct][2] = m4.z ? s[ct][2] * scale : -1e9f;
        s[ct][3] = m4.w ? s[ct][3] * scale : -1e9f;
      } else {
        #pragma unroll
        for (int r = 0; r < 4; ++r) s[ct][r] *= scale;
      }
    }
    float mx = -3e38f;
    #pragma unroll
    for (int ct = 0; ct < 16; ++ct)
      #pragma unroll
      for (int r = 0; r < 4; ++r) mx = fmaxf(mx, s[ct][r]);
    mx = fmaxf(mx, __shfl_xor(mx, 16, 64));
    mx = fmaxf(mx, __shfl_xor(mx, 32, 64));
    float sum = 0.f;
    #pragma unroll
    for (int ct = 0; ct < 16; ++ct)
      #pragma unroll
      for (int r = 0; r < 4; ++r) {
        float p = __expf(s[ct][r] - mx);
        s[ct][r] = p; sum += p;
      }
    sum += __shfl_xor(sum, 16, 64);
    sum += __shfl_xor(sum, 32, 64);
    float inv = fast_rcp(sum);
    #pragma unroll
    for (int ct = 0; ct < 16; ++ct) {
      ushort4 pk;
      pk.x = f2bf_fast(s[ct][0] * inv); pk.y = f2bf_fast(s[ct][1] * inv);
      pk.z = f2bf_fast(s[ct][2] * inv); pk.w = f2bf_fast(s[ct][3] * inv);
      *(ushort4*)&Psh[wv][lr][ct * 16 + lg * 4] = pk;
    }
    f32x4 o[2] = {zero, zero};
    __builtin_amdgcn_s_setprio(1);
    #pragma unroll
    for (int ks = 0; ks < 8; ++ks) {
      short8 pa = *(const short8*)&Psh[wv][lr][ks * 32 + lg * 8];
      #pragma unroll
      for (int c2 = 0; c2 < 2; ++c2) {
        short8 vbf = *(const short8*)&Vtsh[c2 * 16 + lr][ks * 32 + lg * 8];
        o[c2] = __builtin_amdgcn_mfma_f32_16x16x32_bf16(vbf, pa, o[c2], 0, 0, 0);
      }
    }
    __builtin_amdgcn_s_setprio(0);
    // o[c2][r] = O[qrow=lr][d = c2*16 + lg*4 + r]
    #pragma unroll
    for (int c2 = 0; c2 < 2; ++c2) {
      ushort4 ok;
      ok.x = f2bf_fast(o[c2][0]); ok.y = f2bf_fast(o[c2][1]);
      ok.z = f2bf_fast(o[c2][2]); ok.w = f2bf_fast(o[c2][3]);
      *(ushort4*)(O + sb + (size_t)(row0 + lr) * 256 + hc + c2 * 16 + lg * 4) = ok;
    }
  }
}

// ---------------- fused rms + FFN (known-good): 4 blocks/CU ------------------
// 256 thr / 4 waves / 64 rows / 16 rows per wave. Single 32KB weight buffer,
// two barriers per chunk, 37KB LDS. rms prologue keeps x as bf16 (32 VGPRs):
// ss accumulated in fp32 at load, then in-place rescale. oacc 64 AGPR +
// xfrag 32 + temps <= 128 unified -> __launch_bounds__(256,4) = 4 blocks/CU.
__global__ __launch_bounds__(256, 4) void ffn_kernel(
    float* __restrict__ hio, const float* __restrict__ nw,
    const unsigned short* __restrict__ W1F, const unsigned short* __restrict__ W2F,
    const float* __restrict__ b1, const float* __restrict__ b2) {
  __shared__ __align__(16) unsigned short Wbuf[16384];  // W1s 0..8191 | W2s 8192..
  __shared__ __align__(16) unsigned short Psh[4][16][36];
  int tid = threadIdx.x;
  int wv = tid >> 6, lane = tid & 63, lr = lane & 15, lg = lane >> 4;
  int wrow = blockIdx.x * 64 + wv * 16;
  const float* rp = hio + (size_t)(wrow + lr) * 256;
  short8 xfrag[8];
  float ss = 0.f;
  #pragma unroll
  for (int ks = 0; ks < 8; ++ks) {
    float4 a = *(const float4*)(rp + ks * 32 + lg * 8);
    float4 b = *(const float4*)(rp + ks * 32 + lg * 8 + 4);
    ss += a.x * a.x + a.y * a.y + a.z * a.z + a.w * a.w;
    ss += b.x * b.x + b.y * b.y + b.z * b.z + b.w * b.w;
    short8 xf;
    xf[0] = (short)f2bf_fast(a.x); xf[1] = (short)f2bf_fast(a.y);
    xf[2] = (short)f2bf_fast(a.z); xf[3] = (short)f2bf_fast(a.w);
    xf[4] = (short)f2bf_fast(b.x); xf[5] = (short)f2bf_fast(b.y);
    xf[6] = (short)f2bf_fast(b.z); xf[7] = (short)f2bf_fast(b.w);
    xfrag[ks] = xf;
  }
  ss += __shfl_xor(ss, 16, 64);
  ss += __shfl_xor(ss, 32, 64);
  float sc = fast_rsq(ss * 0.00390625f + 1e-6f);
  #pragma unroll
  for (int ks = 0; ks < 8; ++ks) {
    float4 wa = *(const float4*)(nw + ks * 32 + lg * 8);
    float4 wb = *(const float4*)(nw + ks * 32 + lg * 8 + 4);
    short8 xf = xfrag[ks], af;
    af[0] = (short)f2bf_fast(bf2f(xf[0]) * sc * wa.x);
    af[1] = (short)f2bf_fast(bf2f(xf[1]) * sc * wa.y);
    af[2] = (short)f2bf_fast(bf2f(xf[2]) * sc * wa.z);
    af[3] = (short)f2bf_fast(bf2f(xf[3]) * sc * wa.w);
    af[4] = (short)f2bf_fast(bf2f(xf[4]) * sc * wb.x);
    af[5] = (short)f2bf_fast(bf2f(xf[5]) * sc * wb.y);
    af[6] = (short)f2bf_fast(bf2f(xf[6]) * sc * wb.z);
    af[7] = (short)f2bf_fast(bf2f(xf[7]) * sc * wb.w);
    xfrag[ks] = af;
  }
  f32x4 zero = {0.f, 0.f, 0.f, 0.f};
  f32x4 oacc[16];
  #pragma unroll
  for (int ct = 0; ct < 16; ++ct) oacc[ct] = zero;
  for (int fc = 0; fc < 32; ++fc) {
    __syncthreads();  // all waves done reading previous chunk
    #pragma unroll
    for (int i = 0; i < 8; ++i) {
      int s = wv * 8 + i;
      const unsigned short* srcp = (s < 16) ? (W1F + (size_t)fc * 8192 + s * 512)
                                            : (W2F + (size_t)fc * 8192 + (s - 16) * 512);
      load_lds16(srcp + lane * 8, &Wbuf[s * 512]);
    }
    __syncthreads();  // staging complete (vmcnt drain + barrier)
    const unsigned short* W1s = &Wbuf[0];
    const unsigned short* W2s = &Wbuf[8192];
    f32x4 hacc[2];
    hacc[0] = zero; hacc[1] = zero;
    #pragma unroll
    for (int ks = 0; ks < 8; ++ks) {
      #pragma unroll
      for (int ct = 0; ct < 2; ++ct) {
        short8 w1f = *(const short8*)&W1s[(ct * 8 + ks) * 512 + lane * 8];
        // swapped: D[ff][xrow] -> lane holds 4 consecutive ff for xrow=lr
        hacc[ct] = __builtin_amdgcn_mfma_f32_16x16x32_bf16(w1f, xfrag[ks], hacc[ct], 0, 0, 0);
      }
    }
    #pragma unroll
    for (int ct = 0; ct < 2; ++ct) {
      float4 bb = *(const float4*)(b1 + fc * 32 + ct * 16 + lg * 4);
      ushort4 pk;
      float hv = hacc[ct][0] + bb.x;
      pk.x = f2bf_fast(hv * fast_rcp(1.0f + __expf(-1.5957691216057308f * fmaf(0.044715f * hv, hv * hv, hv))));
      hv = hacc[ct][1] + bb.y;
      pk.y = f2bf_fast(hv * fast_rcp(1.0f + __expf(-1.5957691216057308f * fmaf(0.044715f * hv, hv * hv, hv))));
      hv = hacc[ct][2] + bb.z;
      pk.z = f2bf_fast(hv * fast_rcp(1.0f + __expf(-1.5957691216057308f * fmaf(0.044715f * hv, hv * hv, hv))));
      hv = hacc[ct][3] + bb.w;
      pk.w = f2bf_fast(hv * fast_rcp(1.0f + __expf(-1.5957691216057308f * fmaf(0.044715f * hv, hv * hv, hv))));
      *(ushort4*)&Psh[wv][lr][ct * 16 + lg * 4] = pk;  // [xrow=lr][ff]
    }
    short8 pa = *(const short8*)&Psh[wv][lr][lg * 8];
    #pragma unroll
    for (int ct2 = 0; ct2 < 16; ++ct2) {
      short8 bw2 = *(const short8*)&W2s[ct2 * 512 + lane * 8];
      oacc[ct2] = __builtin_amdgcn_mfma_f32_16x16x32_bf16(bw2, pa, oacc[ct2], 0, 0, 0);
    }
  }
  // epilogue: lane holds 4 consecutive out-cols for row = wrow + lr
  size_t rbase = (size_t)(wrow + lr) * 256;
  #pragma unroll
  for (int ct2 = 0; ct2 < 16; ++ct2) {
    int col = ct2 * 16 + lg * 4;
    float4 bb2 = *(const float4*)(b2 + col);
    float4 cur = *(const float4*)(hio + rbase + col);
    cur.x += oacc[ct2][0] + bb2.x;
    cur.y += oacc[ct2][1] + bb2.y;
    cur.z += oacc[ct2][2] + bb2.z;
    cur.w += oacc[ct2][3] + bb2.w;
    *(float4*)(hio + rbase + col) = cur;
  }
}

extern "C" void kernel_launch(void* const* d_in, const int* in_sizes, int n_in,
                              void* d_out, int out_size, void* d_ws, size_t ws_size,
                              hipStream_t stream) {
  (void)in_sizes; (void)n_in; (void)out_size;
  const float* h   = (const float*)d_in[0];
  const int* smask = (const int*)d_in[1];
  const float* ntw = (const float*)d_in[2];
  const float* nsw = (const float*)d_in[3];
  const float* nfw = (const float*)d_in[4];
  const float* wq_t = (const float*)d_in[5];
  const float* wk_t = (const float*)d_in[6];
  const float* wv_t = (const float*)d_in[7];
  const float* wo_t = (const float*)d_in[8];
  const float* wq_s = (const float*)d_in[9];
  const float* wk_s = (const float*)d_in[10];
  const float* wv_s = (const float*)d_in[11];
  const float* wo_s = (const float*)d_in[12];
  const float* w1  = (const float*)d_in[13];
  const float* b1  = (const float*)d_in[14];
  const float* w2  = (const float*)d_in[15];
  const float* b2  = (const float*)d_in[16];
  float* out = (float*)d_out;
  unsigned short* pool = (unsigned short*)d_ws;

  unsigned short* WQKVtF = pool;                 // tiles 0..47
  unsigned short* WOtF   = pool + 196608;        // tiles 48..63
  unsigned short* WQKVsF = pool + 262144;        // tiles 64..111
  unsigned short* WOsF   = pool + 458752;        // tiles 112..127
  unsigned short* W1F    = pool + 524288;
  unsigned short* W2F    = pool + 786432;

  size_t wbytes = 1048576ull * 2;
  size_t avail = (ws_size > wbytes) ? (ws_size - wbytes) : 0;
  long long scl = (long long)(avail / 524288ull);  // 4 buffers x 128KB per sequence
  int SC = scl < 1 ? 1 : (scl > 512 ? 512 : (int)scl);
  unsigned short* xnorm = pool + 1048576;  // attention output buffer
  unsigned short* qb = xnorm + (size_t)SC * 65536;
  unsigned short* kb = qb + (size_t)SC * 65536;
  unsigned short* vb = kb + (size_t)SC * 65536;

  convw_kernel<<<4096, 256, 0, stream>>>(wq_t, wk_t, wv_t, wo_t, wq_s, wk_s, wv_s,
                                         wo_s, w1, w2, pool);

  // ---- stage 1: time attention over (b,n) sequences (512 of them) ----
  for (int s0 = 0; s0 < 512; s0 += SC) {
    int ns = (512 - s0 < SC) ? (512 - s0) : SC;
    int rows = ns * 256;
    qkv_kernel<0><<<rows / 128, 256, 0, stream>>>(h + (size_t)s0 * 65536, ntw, WQKVtF,
                                                  qb, kb, vb, 0);
    attn_kernel<0><<<dim3(8, ns), 256, 0, stream>>>(qb, kb, vb, xnorm, nullptr, 0);
    gemm256_kernel<1><<<rows / 128, 256, 0, stream>>>(xnorm, WOtF,
        h + (size_t)s0 * 65536, out + (size_t)s0 * 65536, 0);
  }

  // ---- stage 2: stock attention over gathered active-t slices (92 sequences) ----
  int SC2 = SC < 92 ? SC : 92;
  for (int s0 = 0; s0 < 92; s0 += SC2) {
    int ns = (92 - s0 < SC2) ? (92 - s0) : SC2;
    int rows = ns * 256;
    qkv_kernel<1><<<rows / 128, 256, 0, stream>>>(out, nsw, WQKVsF, qb, kb, vb, s0 * 256);
    attn_kernel<1><<<dim3(8, ns), 256, 0, stream>>>(qb, kb, vb, xnorm, smask, s0);
    gemm256_kernel<2><<<rows / 128, 256, 0, stream>>>(xnorm, WOsF, nullptr, out, s0 * 256);
  }

  // ---- stage 3: fused rms + FFN (single dispatch, 2048 blocks x 256 threads) ----
  ffn_kernel<<<2048, 256, 0, stream>>>(out, nfw, W1F, W2F, b1, b2);
}

// Round 19
// 629.607 us; speedup vs baseline: 1.1299x; 1.0091x over previous
//
#include <hip/hip_runtime.h>
#include <hip/hip_bf16.h>

typedef __attribute__((ext_vector_type(8))) short short8;
typedef __attribute__((ext_vector_type(4))) float f32x4;

#define TP 46  // active time steps: 30 strided + 16 dense

// raw barrier + counted vmcnt (T3/T4): never drain vmcnt to 0 in a steady loop
#define SBAR() asm volatile("s_barrier" ::: "memory")
#define VMCNT4() asm volatile("s_waitcnt vmcnt(4)" ::: "memory")
#define VMCNT0() asm volatile("s_waitcnt vmcnt(0)" ::: "memory")

__device__ __forceinline__ unsigned short f2bf(float f) {  // RNE (weights, one-time)
  unsigned int u = __float_as_uint(f);
  u = (u + 0x7fff + ((u >> 16) & 1)) >> 16;
  return (unsigned short)u;
}
__device__ __forceinline__ unsigned short f2bf_fast(float f) {
  return (unsigned short)((__float_as_uint(f) + 0x8000u) >> 16);
}
__device__ __forceinline__ float bf2f(short u) {
  return __uint_as_float((unsigned)(unsigned short)u << 16);
}
__device__ __forceinline__ float fast_rcp(float x) {
#if __has_builtin(__builtin_amdgcn_rcpf)
  return __builtin_amdgcn_rcpf(x);
#else
  return 1.0f / x;
#endif
}
__device__ __forceinline__ float fast_rsq(float x) {
#if __has_builtin(__builtin_amdgcn_rsqf)
  return __builtin_amdgcn_rsqf(x);
#else
  return rsqrtf(x);
#endif
}

__device__ __forceinline__ int act_t(int j) { return j < 30 ? (j << 3) : (210 + j); }

// async 16B/lane global->LDS: lds base must be wave-uniform; HW writes lane i at base+i*16
__device__ __forceinline__ void load_lds16(const unsigned short* g, unsigned short* lds_base) {
#if __has_builtin(__builtin_amdgcn_global_load_lds)
  __builtin_amdgcn_global_load_lds(
      (const __attribute__((address_space(1))) unsigned int*)(unsigned long long)g,
      (__attribute__((address_space(3))) unsigned int*)(unsigned int)(unsigned long long)lds_base,
      16, 0, 0);
#else
  int lane = threadIdx.x & 63;
  *(short8*)(lds_base + lane * 8) = *(const short8*)g;
#endif
}

// ---------------- weight convert to fragment-ordered bf16 ----------------
// pool elems: 128 tiles of 4096 for QKV/O (frag-ordered A-operand for swapped
// mfma):  tiles 0..15 Wq_t, 16..31 Wk_t, 32..47 Wv_t, 48..63 Wo_t,
//         64..79 Wq_s, 80..95 Wk_s, 96..111 Wv_s, 112..127 Wo_s.
// tile off = tile*4096 + ks*512 + lane*8 + e -> w[(ks*32+lg*8+e)*256 + ct*16+lr]
// W1F 524288: ((fc*2+ct)*8+ks)*512+lane*8+e -> w1[(ks*32+lg*8+e)*1024 + fc*32+ct*16+lr]
// W2F 786432: (fc*16+ct2)*512+lane*8+e2     -> w2[(fc*32+lg*8+e2)*256 + ct2*16+lr]
__global__ __launch_bounds__(256) void convw_kernel(
    const float* __restrict__ wq_t, const float* __restrict__ wk_t,
    const float* __restrict__ wv_t, const float* __restrict__ wo_t,
    const float* __restrict__ wq_s, const float* __restrict__ wk_s,
    const float* __restrict__ wv_s, const float* __restrict__ wo_s,
    const float* __restrict__ w1, const float* __restrict__ w2,
    unsigned short* __restrict__ pool) {
  int idx = blockIdx.x * 256 + threadIdx.x;
  float v;
  if (idx < 524288) {
    int tile = idx >> 12, local = idx & 4095;
    int ks = local >> 9, q = local & 511;
    int l = q >> 3, e = q & 7;
    int lr = l & 15, lg = l >> 4;
    int ct = tile & 15, grp = tile >> 4;
    const float* s = (grp == 0) ? wq_t : (grp == 1) ? wk_t : (grp == 2) ? wv_t :
                     (grp == 3) ? wo_t : (grp == 4) ? wq_s : (grp == 5) ? wk_s :
                     (grp == 6) ? wv_s : wo_s;
    v = s[(size_t)(ks * 32 + lg * 8 + e) * 256 + ct * 16 + lr];
  } else if (idx < 786432) {
    int local = idx - 524288;
    int e = local & 7, t = local >> 3;
    int lane = t & 63, ks = (t >> 6) & 7, ct = (t >> 9) & 1, fc = t >> 10;
    int lr = lane & 15, lg = lane >> 4;
    v = w1[(size_t)(ks * 32 + lg * 8 + e) * 1024 + fc * 32 + ct * 16 + lr];
  } else {
    int local = idx - 786432;
    int e2 = local & 7, t = local >> 3;
    int lane = t & 63, ct2 = (t >> 6) & 15, fc = t >> 10;
    int lr = lane & 15, lg = lane >> 4;
    v = w2[(size_t)(fc * 32 + lg * 8 + e2) * 256 + ct2 * 16 + lr];
  }
  pool[idx] = f2bf(v);
}

// ---------------- fused rmsnorm + QKV projection (counted-vmcnt pipeline) ----
// 256 thr / 4 waves / 128 rows. rms in-register. 48 weight tiles consumed as
// 24 rounds of 16KB pairs, double-buffered; 2 raw barriers + vmcnt(4) per
// round. T5 setprio around the MFMA cluster (inter-block role diversity:
// 4 blocks/CU at unsynchronized phases, same mechanism that paid in attn).
template<int GATHER>
__global__ __launch_bounds__(256) void qkv_kernel(
    const float* __restrict__ src, const float* __restrict__ nw,
    const unsigned short* __restrict__ WF,  // 48 fragment-ordered tiles
    unsigned short* __restrict__ qb, unsigned short* __restrict__ kb,
    unsigned short* __restrict__ vb, int row_base) {
  __shared__ __align__(16) unsigned short Wbuf[2][8192];
  int tid = threadIdx.x, wv = tid >> 6, lane = tid & 63, lr = lane & 15, lg = lane >> 4;
  int row0 = blockIdx.x * 128 + wv * 32;
  short8 afrag[2][8];
  #pragma unroll
  for (int rt = 0; rt < 2; ++rt) {
    int lrow = row0 + rt * 16 + lr;
    const float* rp;
    if (GATHER) {
      int gr = row_base + lrow;
      int b = gr / 11776; int rem = gr - b * 11776;
      int j = rem >> 8, n = rem & 255;
      rp = src + (((size_t)((b << 8) + n) << 8) + act_t(j)) * 256;
    } else {
      rp = src + (size_t)lrow * 256;
    }
    float4 x[16];
    #pragma unroll
    for (int ks = 0; ks < 8; ++ks) {
      x[ks * 2]     = *(const float4*)(rp + ks * 32 + lg * 8);
      x[ks * 2 + 1] = *(const float4*)(rp + ks * 32 + lg * 8 + 4);
    }
    float ss = 0.f;
    #pragma unroll
    for (int i = 0; i < 16; ++i)
      ss += x[i].x * x[i].x + x[i].y * x[i].y + x[i].z * x[i].z + x[i].w * x[i].w;
    ss += __shfl_xor(ss, 16, 64);
    ss += __shfl_xor(ss, 32, 64);
    float sc = fast_rsq(ss * 0.00390625f + 1e-6f);
    #pragma unroll
    for (int ks = 0; ks < 8; ++ks) {
      float4 w0 = *(const float4*)(nw + ks * 32 + lg * 8);
      float4 w1_ = *(const float4*)(nw + ks * 32 + lg * 8 + 4);
      short8 af;
      af[0] = (short)f2bf_fast(x[ks * 2].x * sc * w0.x);
      af[1] = (short)f2bf_fast(x[ks * 2].y * sc * w0.y);
      af[2] = (short)f2bf_fast(x[ks * 2].z * sc * w0.z);
      af[3] = (short)f2bf_fast(x[ks * 2].w * sc * w0.w);
      af[4] = (short)f2bf_fast(x[ks * 2 + 1].x * sc * w1_.x);
      af[5] = (short)f2bf_fast(x[ks * 2 + 1].y * sc * w1_.y);
      af[6] = (short)f2bf_fast(x[ks * 2 + 1].z * sc * w1_.z);
      af[7] = (short)f2bf_fast(x[ks * 2 + 1].w * sc * w1_.w);
      afrag[rt][ks] = af;
    }
  }
  // stage pair 0 (16 x 1KB segments; each wave stages 4)
  #pragma unroll
  for (int i = 0; i < 4; ++i) {
    int s = wv * 4 + i;
    load_lds16(WF + (size_t)s * 512 + lane * 8, &Wbuf[0][s * 512]);
  }
  f32x4 zero = {0.f, 0.f, 0.f, 0.f};
  for (int r = 0; r < 24; ++r) {
    SBAR();  // B1: all waves done computing pair r-1 -> buf[(r+1)&1] reusable
    if (r < 23) {
      #pragma unroll
      for (int i = 0; i < 4; ++i) {
        int s = wv * 4 + i;
        load_lds16(WF + (size_t)(r + 1) * 8192 + s * 512 + lane * 8,
                   &Wbuf[(r + 1) & 1][s * 512]);
      }
      VMCNT4();  // pair r's 4 loads retired; r+1's 4 stay in flight
    } else {
      VMCNT0();
    }
    SBAR();  // B2: every wave has waited its vmcnt -> pair r fully in LDS
    __builtin_amdgcn_s_setprio(1);
    #pragma unroll
    for (int sub = 0; sub < 2; ++sub) {
      int t = r * 2 + sub;
      const unsigned short* Ws = &Wbuf[r & 1][sub * 4096];
      f32x4 a0 = zero, a1 = zero;
      #pragma unroll
      for (int ks = 0; ks < 8; ++ks) {
        short8 bw = *(const short8*)&Ws[ks * 512 + lane * 8];
        a0 = __builtin_amdgcn_mfma_f32_16x16x32_bf16(bw, afrag[0][ks], a0, 0, 0, 0);
        a1 = __builtin_amdgcn_mfma_f32_16x16x32_bf16(bw, afrag[1][ks], a1, 0, 0, 0);
      }
      __builtin_amdgcn_s_setprio(0);
      int m = t >> 4, ct = t & 15;
      unsigned short* dst = (m == 0) ? qb : (m == 1) ? kb : vb;
      ushort4 p0, p1;
      p0.x = f2bf_fast(a0[0]); p0.y = f2bf_fast(a0[1]);
      p0.z = f2bf_fast(a0[2]); p0.w = f2bf_fast(a0[3]);
      p1.x = f2bf_fast(a1[0]); p1.y = f2bf_fast(a1[1]);
      p1.z = f2bf_fast(a1[2]); p1.w = f2bf_fast(a1[3]);
      *(ushort4*)(dst + (size_t)(row0 + lr) * 256 + ct * 16 + lg * 4) = p0;
      *(ushort4*)(dst + (size_t)(row0 + 16 + lr) * 256 + ct * 16 + lg * 4) = p1;
      if (sub == 0) __builtin_amdgcn_s_setprio(1);
    }
  }
}

// ---------------- output projection GEMM (LDS-staged weights) ----------------
// MODE 1: outf = resid + X@W.  MODE 2: scatter-add into h (float4 RMW).
// 8 rounds of 16KB pairs, __syncthreads. T5 setprio around MFMA clusters.
template<int MODE>
__global__ __launch_bounds__(256) void gemm256_kernel(
    const unsigned short* __restrict__ X, const unsigned short* __restrict__ WF,
    const float* __restrict__ resid, float* __restrict__ outf, int row_base) {
  __shared__ __align__(16) unsigned short Wbuf[2][8192];
  int tid = threadIdx.x, wv = tid >> 6, lane = tid & 63, lr = lane & 15, lg = lane >> 4;
  int row0 = blockIdx.x * 128 + wv * 32;
  short8 afrag[2][8];
  size_t rb[2];
  #pragma unroll
  for (int rt = 0; rt < 2; ++rt) {
    int row = row0 + rt * 16 + lr;
    #pragma unroll
    for (int ks = 0; ks < 8; ++ks)
      afrag[rt][ks] = *(const short8*)(X + (size_t)row * 256 + ks * 32 + lg * 8);
    if (MODE == 1) {
      rb[rt] = (size_t)row * 256;
    } else {
      int gr = row_base + row;
      int b = gr / 11776; int rem = gr - b * 11776;
      int j = rem >> 8, n = rem & 255;
      rb[rt] = (((size_t)((b << 8) + n) << 8) + act_t(j)) * 256;
    }
  }
  #pragma unroll
  for (int i = 0; i < 4; ++i) {
    int s = wv * 4 + i;
    load_lds16(WF + (size_t)s * 512 + lane * 8, &Wbuf[0][s * 512]);
  }
  f32x4 zero = {0.f, 0.f, 0.f, 0.f};
  for (int r = 0; r < 8; ++r) {
    __syncthreads();
    if (r < 7) {
      #pragma unroll
      for (int i = 0; i < 4; ++i) {
        int s = wv * 4 + i;
        load_lds16(WF + (size_t)(r + 1) * 8192 + s * 512 + lane * 8,
                   &Wbuf[(r + 1) & 1][s * 512]);
      }
    }
    __syncthreads();
    #pragma unroll
    for (int sub = 0; sub < 2; ++sub) {
      int t = r * 2 + sub;
      const unsigned short* Ws = &Wbuf[r & 1][sub * 4096];
      f32x4 a0 = zero, a1 = zero;
      __builtin_amdgcn_s_setprio(1);
      #pragma unroll
      for (int ks = 0; ks < 8; ++ks) {
        short8 bw = *(const short8*)&Ws[ks * 512 + lane * 8];
        a0 = __builtin_amdgcn_mfma_f32_16x16x32_bf16(bw, afrag[0][ks], a0, 0, 0, 0);
        a1 = __builtin_amdgcn_mfma_f32_16x16x32_bf16(bw, afrag[1][ks], a1, 0, 0, 0);
      }
      __builtin_amdgcn_s_setprio(0);
      int col = t * 16 + lg * 4;
      if (MODE == 1) {
        float4 r0 = *(const float4*)(resid + rb[0] + col);
        float4 r1 = *(const float4*)(resid + rb[1] + col);
        float4 o0, o1;
        o0.x = r0.x + a0[0]; o0.y = r0.y + a0[1]; o0.z = r0.z + a0[2]; o0.w = r0.w + a0[3];
        o1.x = r1.x + a1[0]; o1.y = r1.y + a1[1]; o1.z = r1.z + a1[2]; o1.w = r1.w + a1[3];
        *(float4*)(outf + rb[0] + col) = o0;
        *(float4*)(outf + rb[1] + col) = o1;
      } else {
        float4 c0 = *(const float4*)(outf + rb[0] + col);
        float4 c1 = *(const float4*)(outf + rb[1] + col);
        c0.x += a0[0]; c0.y += a0[1]; c0.z += a0[2]; c0.w += a0[3];
        c1.x += a1[0]; c1.y += a1[1]; c1.z += a1[2]; c1.w += a1[3];
        *(float4*)(outf + rb[0] + col) = c0;
        *(float4*)(outf + rb[1] + col) = c1;
      }
    }
  }
}

// ---------------- attention: one block per (head, seq); seq len 256, hdim 32 ----------------
// Coalesced staging: lane->(row=tid>>2, chunk=tid&3) => 64B-contiguous reads.
// Swapped QK^T; softmax reduce = 2 shfl_xor; swapped PV; vectorized O store.
// T5: setprio(1) around the MFMA clusters (R18: -63us, inter-block diversity).
template<int MASKED>
__global__ __launch_bounds__(256) void attn_kernel(
    const unsigned short* __restrict__ Q, const unsigned short* __restrict__ K,
    const unsigned short* __restrict__ V, unsigned short* __restrict__ O,
    const int* __restrict__ mask, int seq_base) {
  __shared__ unsigned short Ksh[256][40];    // padded
  __shared__ unsigned short Vtsh[32][264];   // V transposed [d][key]
  __shared__ unsigned short Psh[4][16][264]; // per-wave P: [qrow][key]
  int head = blockIdx.x, seq = blockIdx.y;
  int hc = head * 32;
  size_t sb = (size_t)seq * 65536;
  int tid = threadIdx.x;
  {
    int c = tid & 3, rbase = tid >> 2;
    #pragma unroll
    for (int i = 0; i < 4; ++i) {
      int r = rbase + i * 64;
      *(short8*)&Ksh[r][c * 8] = *(const short8*)(K + sb + (size_t)r * 256 + hc + c * 8);
      short8 vv = *(const short8*)(V + sb + (size_t)r * 256 + hc + c * 8);
      #pragma unroll
      for (int e = 0; e < 8; ++e) Vtsh[c * 8 + e][r] = (unsigned short)vv[e];
    }
  }
  __syncthreads();
  int wv = tid >> 6, lane = tid & 63, lr = lane & 15, lg = lane >> 4;
  const float scale = 0.17677669529663687f;  // 1/sqrt(32)
  int mb = 0;
  if (MASKED) mb = (seq_base + seq) / TP;
  f32x4 zero = {0.f, 0.f, 0.f, 0.f};
  for (int rt = 0; rt < 4; ++rt) {
    int row0 = wv * 64 + rt * 16;
    short8 aq = *(const short8*)(Q + sb + (size_t)(row0 + lr) * 256 + hc + lg * 8);
    f32x4 s[16];
    __builtin_amdgcn_s_setprio(1);
    #pragma unroll
    for (int ct = 0; ct < 16; ++ct) {
      short8 kb = *(const short8*)&Ksh[ct * 16 + lr][lg * 8];
      s[ct] = __builtin_amdgcn_mfma_f32_16x16x32_bf16(kb, aq, zero, 0, 0, 0);
    }
    __builtin_amdgcn_s_setprio(0);
    // s[ct][r] = S[qrow=lr][key = ct*16 + lg*4 + r]
    #pragma unroll
    for (int ct = 0; ct < 16; ++ct) {
      if (MASKED) {
        const int4 m4 = *(const int4*)(mask + mb * 256 + ct * 16 + lg * 4);
        s[ct][0] = m4.x ? s[ct][0] * scale : -1e9f;
        s[ct][1] = m4.y ? s[ct][1] * scale : -1e9f;
        s[ct][2] = m4.z ? s[ct][2] * scale : -1e9f;
        s[ct][3] = m4.w ? s[ct][3] * scale : -1e9f;
      } else {
        #pragma unroll
        for (int r = 0; r < 4; ++r) s[ct][r] *= scale;
      }
    }
    float mx = -3e38f;
    #pragma unroll
    for (int ct = 0; ct < 16; ++ct)
      #pragma unroll
      for (int r = 0; r < 4; ++r) mx = fmaxf(mx, s[ct][r]);
    mx = fmaxf(mx, __shfl_xor(mx, 16, 64));
    mx = fmaxf(mx, __shfl_xor(mx, 32, 64));
    float sum = 0.f;
    #pragma unroll
    for (int ct = 0; ct < 16; ++ct)
      #pragma unroll
      for (int r = 0; r < 4; ++r) {
        float p = __expf(s[ct][r] - mx);
        s[ct][r] = p; sum += p;
      }
    sum += __shfl_xor(sum, 16, 64);
    sum += __shfl_xor(sum, 32, 64);
    float inv = fast_rcp(sum);
    #pragma unroll
    for (int ct = 0; ct < 16; ++ct) {
      ushort4 pk;
      pk.x = f2bf_fast(s[ct][0] * inv); pk.y = f2bf_fast(s[ct][1] * inv);
      pk.z = f2bf_fast(s[ct][2] * inv); pk.w = f2bf_fast(s[ct][3] * inv);
      *(ushort4*)&Psh[wv][lr][ct * 16 + lg * 4] = pk;
    }
    f32x4 o[2] = {zero, zero};
    __builtin_amdgcn_s_setprio(1);
    #pragma unroll
    for (int ks = 0; ks < 8; ++ks) {
      short8 pa = *(const short8*)&Psh[wv][lr][ks * 32 + lg * 8];
      #pragma unroll
      for (int c2 = 0; c2 < 2; ++c2) {
        short8 vbf = *(const short8*)&Vtsh[c2 * 16 + lr][ks * 32 + lg * 8];
        o[c2] = __builtin_amdgcn_mfma_f32_16x16x32_bf16(vbf, pa, o[c2], 0, 0, 0);
      }
    }
    __builtin_amdgcn_s_setprio(0);
    // o[c2][r] = O[qrow=lr][d = c2*16 + lg*4 + r]
    #pragma unroll
    for (int c2 = 0; c2 < 2; ++c2) {
      ushort4 ok;
      ok.x = f2bf_fast(o[c2][0]); ok.y = f2bf_fast(o[c2][1]);
      ok.z = f2bf_fast(o[c2][2]); ok.w = f2bf_fast(o[c2][3]);
      *(ushort4*)(O + sb + (size_t)(row0 + lr) * 256 + hc + c2 * 16 + lg * 4) = ok;
    }
  }
}

// ---------------- fused rms + FFN (known-good): 4 blocks/CU ------------------
// 256 thr / 4 waves / 64 rows / 16 rows per wave. Single 32KB weight buffer,
// two barriers per chunk, 37KB LDS. rms prologue keeps x as bf16 (32 VGPRs):
// ss accumulated in fp32 at load, then in-place rescale. oacc 64 AGPR +
// xfrag 32 + temps <= 128 unified -> __launch_bounds__(256,4) = 4 blocks/CU.
__global__ __launch_bounds__(256, 4) void ffn_kernel(
    float* __restrict__ hio, const float* __restrict__ nw,
    const unsigned short* __restrict__ W1F, const unsigned short* __restrict__ W2F,
    const float* __restrict__ b1, const float* __restrict__ b2) {
  __shared__ __align__(16) unsigned short Wbuf[16384];  // W1s 0..8191 | W2s 8192..
  __shared__ __align__(16) unsigned short Psh[4][16][36];
  int tid = threadIdx.x;
  int wv = tid >> 6, lane = tid & 63, lr = lane & 15, lg = lane >> 4;
  int wrow = blockIdx.x * 64 + wv * 16;
  const float* rp = hio + (size_t)(wrow + lr) * 256;
  short8 xfrag[8];
  float ss = 0.f;
  #pragma unroll
  for (int ks = 0; ks < 8; ++ks) {
    float4 a = *(const float4*)(rp + ks * 32 + lg * 8);
    float4 b = *(const float4*)(rp + ks * 32 + lg * 8 + 4);
    ss += a.x * a.x + a.y * a.y + a.z * a.z + a.w * a.w;
    ss += b.x * b.x + b.y * b.y + b.z * b.z + b.w * b.w;
    short8 xf;
    xf[0] = (short)f2bf_fast(a.x); xf[1] = (short)f2bf_fast(a.y);
    xf[2] = (short)f2bf_fast(a.z); xf[3] = (short)f2bf_fast(a.w);
    xf[4] = (short)f2bf_fast(b.x); xf[5] = (short)f2bf_fast(b.y);
    xf[6] = (short)f2bf_fast(b.z); xf[7] = (short)f2bf_fast(b.w);
    xfrag[ks] = xf;
  }
  ss += __shfl_xor(ss, 16, 64);
  ss += __shfl_xor(ss, 32, 64);
  float sc = fast_rsq(ss * 0.00390625f + 1e-6f);
  #pragma unroll
  for (int ks = 0; ks < 8; ++ks) {
    float4 wa = *(const float4*)(nw + ks * 32 + lg * 8);
    float4 wb = *(const float4*)(nw + ks * 32 + lg * 8 + 4);
    short8 xf = xfrag[ks], af;
    af[0] = (short)f2bf_fast(bf2f(xf[0]) * sc * wa.x);
    af[1] = (short)f2bf_fast(bf2f(xf[1]) * sc * wa.y);
    af[2] = (short)f2bf_fast(bf2f(xf[2]) * sc * wa.z);
    af[3] = (short)f2bf_fast(bf2f(xf[3]) * sc * wa.w);
    af[4] = (short)f2bf_fast(bf2f(xf[4]) * sc * wb.x);
    af[5] = (short)f2bf_fast(bf2f(xf[5]) * sc * wb.y);
    af[6] = (short)f2bf_fast(bf2f(xf[6]) * sc * wb.z);
    af[7] = (short)f2bf_fast(bf2f(xf[7]) * sc * wb.w);
    xfrag[ks] = af;
  }
  f32x4 zero = {0.f, 0.f, 0.f, 0.f};
  f32x4 oacc[16];
  #pragma unroll
  for (int ct = 0; ct < 16; ++ct) oacc[ct] = zero;
  for (int fc = 0; fc < 32; ++fc) {
    __syncthreads();  // all waves done reading previous chunk
    #pragma unroll
    for (int i = 0; i < 8; ++i) {
      int s = wv * 8 + i;
      const unsigned short* srcp = (s < 16) ? (W1F + (size_t)fc * 8192 + s * 512)
                                            : (W2F + (size_t)fc * 8192 + (s - 16) * 512);
      load_lds16(srcp + lane * 8, &Wbuf[s * 512]);
    }
    __syncthreads();  // staging complete (vmcnt drain + barrier)
    const unsigned short* W1s = &Wbuf[0];
    const unsigned short* W2s = &Wbuf[8192];
    f32x4 hacc[2];
    hacc[0] = zero; hacc[1] = zero;
    #pragma unroll
    for (int ks = 0; ks < 8; ++ks) {
      #pragma unroll
      for (int ct = 0; ct < 2; ++ct) {
        short8 w1f = *(const short8*)&W1s[(ct * 8 + ks) * 512 + lane * 8];
        // swapped: D[ff][xrow] -> lane holds 4 consecutive ff for xrow=lr
        hacc[ct] = __builtin_amdgcn_mfma_f32_16x16x32_bf16(w1f, xfrag[ks], hacc[ct], 0, 0, 0);
      }
    }
    #pragma unroll
    for (int ct = 0; ct < 2; ++ct) {
      float4 bb = *(const float4*)(b1 + fc * 32 + ct * 16 + lg * 4);
      ushort4 pk;
      float hv = hacc[ct][0] + bb.x;
      pk.x = f2bf_fast(hv * fast_rcp(1.0f + __expf(-1.5957691216057308f * fmaf(0.044715f * hv, hv * hv, hv))));
      hv = hacc[ct][1] + bb.y;
      pk.y = f2bf_fast(hv * fast_rcp(1.0f + __expf(-1.5957691216057308f * fmaf(0.044715f * hv, hv * hv, hv))));
      hv = hacc[ct][2] + bb.z;
      pk.z = f2bf_fast(hv * fast_rcp(1.0f + __expf(-1.5957691216057308f * fmaf(0.044715f * hv, hv * hv, hv))));
      hv = hacc[ct][3] + bb.w;
      pk.w = f2bf_fast(hv * fast_rcp(1.0f + __expf(-1.5957691216057308f * fmaf(0.044715f * hv, hv * hv, hv))));
      *(ushort4*)&Psh[wv][lr][ct * 16 + lg * 4] = pk;  // [xrow=lr][ff]
    }
    short8 pa = *(const short8*)&Psh[wv][lr][lg * 8];
    #pragma unroll
    for (int ct2 = 0; ct2 < 16; ++ct2) {
      short8 bw2 = *(const short8*)&W2s[ct2 * 512 + lane * 8];
      oacc[ct2] = __builtin_amdgcn_mfma_f32_16x16x32_bf16(bw2, pa, oacc[ct2], 0, 0, 0);
    }
  }
  // epilogue: lane holds 4 consecutive out-cols for row = wrow + lr
  size_t rbase = (size_t)(wrow + lr) * 256;
  #pragma unroll
  for (int ct2 = 0; ct2 < 16; ++ct2) {
    int col = ct2 * 16 + lg * 4;
    float4 bb2 = *(const float4*)(b2 + col);
    float4 cur = *(const float4*)(hio + rbase + col);
    cur.x += oacc[ct2][0] + bb2.x;
    cur.y += oacc[ct2][1] + bb2.y;
    cur.z += oacc[ct2][2] + bb2.z;
    cur.w += oacc[ct2][3] + bb2.w;
    *(float4*)(hio + rbase + col) = cur;
  }
}

extern "C" void kernel_launch(void* const* d_in, const int* in_sizes, int n_in,
                              void* d_out, int out_size, void* d_ws, size_t ws_size,
                              hipStream_t stream) {
  (void)in_sizes; (void)n_in; (void)out_size;
  const float* h   = (const float*)d_in[0];
  const int* smask = (const int*)d_in[1];
  const float* ntw = (const float*)d_in[2];
  const float* nsw = (const float*)d_in[3];
  const float* nfw = (const float*)d_in[4];
  const float* wq_t = (const float*)d_in[5];
  const float* wk_t = (const float*)d_in[6];
  const float* wv_t = (const float*)d_in[7];
  const float* wo_t = (const float*)d_in[8];
  const float* wq_s = (const float*)d_in[9];
  const float* wk_s = (const float*)d_in[10];
  const float* wv_s = (const float*)d_in[11];
  const float* wo_s = (const float*)d_in[12];
  const float* w1  = (const float*)d_in[13];
  const float* b1  = (const float*)d_in[14];
  const float* w2  = (const float*)d_in[15];
  const float* b2  = (const float*)d_in[16];
  float* out = (float*)d_out;
  unsigned short* pool = (unsigned short*)d_ws;

  unsigned short* WQKVtF = pool;                 // tiles 0..47
  unsigned short* WOtF   = pool + 196608;        // tiles 48..63
  unsigned short* WQKVsF = pool + 262144;        // tiles 64..111
  unsigned short* WOsF   = pool + 458752;        // tiles 112..127
  unsigned short* W1F    = pool + 524288;
  unsigned short* W2F    = pool + 786432;

  size_t wbytes = 1048576ull * 2;
  size_t avail = (ws_size > wbytes) ? (ws_size - wbytes) : 0;
  long long scl = (long long)(avail / 524288ull);  // 4 buffers x 128KB per sequence
  int SC = scl < 1 ? 1 : (scl > 512 ? 512 : (int)scl);
  unsigned short* xnorm = pool + 1048576;  // attention output buffer
  unsigned short* qb = xnorm + (size_t)SC * 65536;
  unsigned short* kb = qb + (size_t)SC * 65536;
  unsigned short* vb = kb + (size_t)SC * 65536;

  convw_kernel<<<4096, 256, 0, stream>>>(wq_t, wk_t, wv_t, wo_t, wq_s, wk_s, wv_s,
                                         wo_s, w1, w2, pool);

  // ---- stage 1: time attention over (b,n) sequences (512 of them) ----
  for (int s0 = 0; s0 < 512; s0 += SC) {
    int ns = (512 - s0 < SC) ? (512 - s0) : SC;
    int rows = ns * 256;
    qkv_kernel<0><<<rows / 128, 256, 0, stream>>>(h + (size_t)s0 * 65536, ntw, WQKVtF,
                                                  qb, kb, vb, 0);
    attn_kernel<0><<<dim3(8, ns), 256, 0, stream>>>(qb, kb, vb, xnorm, nullptr, 0);
    gemm256_kernel<1><<<rows / 128, 256, 0, stream>>>(xnorm, WOtF,
        h + (size_t)s0 * 65536, out + (size_t)s0 * 65536, 0);
  }

  // ---- stage 2: stock attention over gathered active-t slices (92 sequences) ----
  int SC2 = SC < 92 ? SC : 92;
  for (int s0 = 0; s0 < 92; s0 += SC2) {
    int ns = (92 - s0 < SC2) ? (92 - s0) : SC2;
    int rows = ns * 256;
    qkv_kernel<1><<<rows / 128, 256, 0, stream>>>(out, nsw, WQKVsF, qb, kb, vb, s0 * 256);
    attn_kernel<1><<<dim3(8, ns), 256, 0, stream>>>(qb, kb, vb, xnorm, smask, s0);
    gemm256_kernel<2><<<rows / 128, 256, 0, stream>>>(xnorm, WOsF, nullptr, out, s0 * 256);
  }

  // ---- stage 3: fused rms + FFN (single dispatch, 2048 blocks x 256 threads) ----
  ffn_kernel<<<2048, 256, 0, stream>>>(out, nfw, W1F, W2F, b1, b2);
}

// Round 20
// 623.823 us; speedup vs baseline: 1.1404x; 1.0093x over previous
//
#include <hip/hip_runtime.h>
#include <hip/hip_bf16.h>

typedef __attribute__((ext_vector_type(8))) short short8;
typedef __attribute__((ext_vector_type(4))) float f32x4;

#define TP 46  // active time steps: 30 strided + 16 dense

// raw barrier + counted vmcnt (T3/T4): never drain vmcnt to 0 in a steady loop
#define SBAR() asm volatile("s_barrier" ::: "memory")
#define VMCNT4() asm volatile("s_waitcnt vmcnt(4)" ::: "memory")
#define VMCNT0() asm volatile("s_waitcnt vmcnt(0)" ::: "memory")

__device__ __forceinline__ unsigned short f2bf(float f) {  // RNE (weights, one-time)
  unsigned int u = __float_as_uint(f);
  u = (u + 0x7fff + ((u >> 16) & 1)) >> 16;
  return (unsigned short)u;
}
__device__ __forceinline__ unsigned short f2bf_fast(float f) {
  return (unsigned short)((__float_as_uint(f) + 0x8000u) >> 16);
}
__device__ __forceinline__ float bf2f(short u) {
  return __uint_as_float((unsigned)(unsigned short)u << 16);
}
__device__ __forceinline__ float fast_rcp(float x) {
#if __has_builtin(__builtin_amdgcn_rcpf)
  return __builtin_amdgcn_rcpf(x);
#else
  return 1.0f / x;
#endif
}
__device__ __forceinline__ float fast_rsq(float x) {
#if __has_builtin(__builtin_amdgcn_rsqf)
  return __builtin_amdgcn_rsqf(x);
#else
  return rsqrtf(x);
#endif
}

__device__ __forceinline__ int act_t(int j) { return j < 30 ? (j << 3) : (210 + j); }

// async 16B/lane global->LDS: lds base must be wave-uniform; HW writes lane i at base+i*16
__device__ __forceinline__ void load_lds16(const unsigned short* g, unsigned short* lds_base) {
#if __has_builtin(__builtin_amdgcn_global_load_lds)
  __builtin_amdgcn_global_load_lds(
      (const __attribute__((address_space(1))) unsigned int*)(unsigned long long)g,
      (__attribute__((address_space(3))) unsigned int*)(unsigned int)(unsigned long long)lds_base,
      16, 0, 0);
#else
  int lane = threadIdx.x & 63;
  *(short8*)(lds_base + lane * 8) = *(const short8*)g;
#endif
}

// ---------------- weight convert to fragment-ordered bf16 ----------------
// pool elems: 128 tiles of 4096 for QKV/O (frag-ordered A-operand for swapped
// mfma):  tiles 0..15 Wq_t, 16..31 Wk_t, 32..47 Wv_t, 48..63 Wo_t,
//         64..79 Wq_s, 80..95 Wk_s, 96..111 Wv_s, 112..127 Wo_s.
// tile off = tile*4096 + ks*512 + lane*8 + e -> w[(ks*32+lg*8+e)*256 + ct*16+lr]
// W1F 524288: ((fc*2+ct)*8+ks)*512+lane*8+e -> w1[(ks*32+lg*8+e)*1024 + fc*32+ct*16+lr]
// W2F 786432: (fc*16+ct2)*512+lane*8+e2     -> w2[(fc*32+lg*8+e2)*256 + ct2*16+lr]
__global__ __launch_bounds__(256) void convw_kernel(
    const float* __restrict__ wq_t, const float* __restrict__ wk_t,
    const float* __restrict__ wv_t, const float* __restrict__ wo_t,
    const float* __restrict__ wq_s, const float* __restrict__ wk_s,
    const float* __restrict__ wv_s, const float* __restrict__ wo_s,
    const float* __restrict__ w1, const float* __restrict__ w2,
    unsigned short* __restrict__ pool) {
  int idx = blockIdx.x * 256 + threadIdx.x;
  float v;
  if (idx < 524288) {
    int tile = idx >> 12, local = idx & 4095;
    int ks = local >> 9, q = local & 511;
    int l = q >> 3, e = q & 7;
    int lr = l & 15, lg = l >> 4;
    int ct = tile & 15, grp = tile >> 4;
    const float* s = (grp == 0) ? wq_t : (grp == 1) ? wk_t : (grp == 2) ? wv_t :
                     (grp == 3) ? wo_t : (grp == 4) ? wq_s : (grp == 5) ? wk_s :
                     (grp == 6) ? wv_s : wo_s;
    v = s[(size_t)(ks * 32 + lg * 8 + e) * 256 + ct * 16 + lr];
  } else if (idx < 786432) {
    int local = idx - 524288;
    int e = local & 7, t = local >> 3;
    int lane = t & 63, ks = (t >> 6) & 7, ct = (t >> 9) & 1, fc = t >> 10;
    int lr = lane & 15, lg = lane >> 4;
    v = w1[(size_t)(ks * 32 + lg * 8 + e) * 1024 + fc * 32 + ct * 16 + lr];
  } else {
    int local = idx - 786432;
    int e2 = local & 7, t = local >> 3;
    int lane = t & 63, ct2 = (t >> 6) & 15, fc = t >> 10;
    int lr = lane & 15, lg = lane >> 4;
    v = w2[(size_t)(fc * 32 + lg * 8 + e2) * 256 + ct2 * 16 + lr];
  }
  pool[idx] = f2bf(v);
}

// ---------------- fused rmsnorm + QKV projection (counted-vmcnt pipeline) ----
// 256 thr / 4 waves / 128 rows. rms in-register. 48 weight tiles consumed as
// 24 rounds of 16KB pairs, double-buffered; 2 raw barriers + vmcnt(4) per
// round. T5 setprio around the MFMA cluster (inter-block role diversity).
template<int GATHER>
__global__ __launch_bounds__(256) void qkv_kernel(
    const float* __restrict__ src, const float* __restrict__ nw,
    const unsigned short* __restrict__ WF,  // 48 fragment-ordered tiles
    unsigned short* __restrict__ qb, unsigned short* __restrict__ kb,
    unsigned short* __restrict__ vb, int row_base) {
  __shared__ __align__(16) unsigned short Wbuf[2][8192];
  int tid = threadIdx.x, wv = tid >> 6, lane = tid & 63, lr = lane & 15, lg = lane >> 4;
  int row0 = blockIdx.x * 128 + wv * 32;
  short8 afrag[2][8];
  #pragma unroll
  for (int rt = 0; rt < 2; ++rt) {
    int lrow = row0 + rt * 16 + lr;
    const float* rp;
    if (GATHER) {
      int gr = row_base + lrow;
      int b = gr / 11776; int rem = gr - b * 11776;
      int j = rem >> 8, n = rem & 255;
      rp = src + (((size_t)((b << 8) + n) << 8) + act_t(j)) * 256;
    } else {
      rp = src + (size_t)lrow * 256;
    }
    float4 x[16];
    #pragma unroll
    for (int ks = 0; ks < 8; ++ks) {
      x[ks * 2]     = *(const float4*)(rp + ks * 32 + lg * 8);
      x[ks * 2 + 1] = *(const float4*)(rp + ks * 32 + lg * 8 + 4);
    }
    float ss = 0.f;
    #pragma unroll
    for (int i = 0; i < 16; ++i)
      ss += x[i].x * x[i].x + x[i].y * x[i].y + x[i].z * x[i].z + x[i].w * x[i].w;
    ss += __shfl_xor(ss, 16, 64);
    ss += __shfl_xor(ss, 32, 64);
    float sc = fast_rsq(ss * 0.00390625f + 1e-6f);
    #pragma unroll
    for (int ks = 0; ks < 8; ++ks) {
      float4 w0 = *(const float4*)(nw + ks * 32 + lg * 8);
      float4 w1_ = *(const float4*)(nw + ks * 32 + lg * 8 + 4);
      short8 af;
      af[0] = (short)f2bf_fast(x[ks * 2].x * sc * w0.x);
      af[1] = (short)f2bf_fast(x[ks * 2].y * sc * w0.y);
      af[2] = (short)f2bf_fast(x[ks * 2].z * sc * w0.z);
      af[3] = (short)f2bf_fast(x[ks * 2].w * sc * w0.w);
      af[4] = (short)f2bf_fast(x[ks * 2 + 1].x * sc * w1_.x);
      af[5] = (short)f2bf_fast(x[ks * 2 + 1].y * sc * w1_.y);
      af[6] = (short)f2bf_fast(x[ks * 2 + 1].z * sc * w1_.z);
      af[7] = (short)f2bf_fast(x[ks * 2 + 1].w * sc * w1_.w);
      afrag[rt][ks] = af;
    }
  }
  // stage pair 0 (16 x 1KB segments; each wave stages 4)
  #pragma unroll
  for (int i = 0; i < 4; ++i) {
    int s = wv * 4 + i;
    load_lds16(WF + (size_t)s * 512 + lane * 8, &Wbuf[0][s * 512]);
  }
  f32x4 zero = {0.f, 0.f, 0.f, 0.f};
  for (int r = 0; r < 24; ++r) {
    SBAR();  // B1: all waves done computing pair r-1 -> buf[(r+1)&1] reusable
    if (r < 23) {
      #pragma unroll
      for (int i = 0; i < 4; ++i) {
        int s = wv * 4 + i;
        load_lds16(WF + (size_t)(r + 1) * 8192 + s * 512 + lane * 8,
                   &Wbuf[(r + 1) & 1][s * 512]);
      }
      VMCNT4();  // pair r's 4 loads retired; r+1's 4 stay in flight
    } else {
      VMCNT0();
    }
    SBAR();  // B2: every wave has waited its vmcnt -> pair r fully in LDS
    __builtin_amdgcn_s_setprio(1);
    #pragma unroll
    for (int sub = 0; sub < 2; ++sub) {
      int t = r * 2 + sub;
      const unsigned short* Ws = &Wbuf[r & 1][sub * 4096];
      f32x4 a0 = zero, a1 = zero;
      #pragma unroll
      for (int ks = 0; ks < 8; ++ks) {
        short8 bw = *(const short8*)&Ws[ks * 512 + lane * 8];
        a0 = __builtin_amdgcn_mfma_f32_16x16x32_bf16(bw, afrag[0][ks], a0, 0, 0, 0);
        a1 = __builtin_amdgcn_mfma_f32_16x16x32_bf16(bw, afrag[1][ks], a1, 0, 0, 0);
      }
      __builtin_amdgcn_s_setprio(0);
      int m = t >> 4, ct = t & 15;
      unsigned short* dst = (m == 0) ? qb : (m == 1) ? kb : vb;
      ushort4 p0, p1;
      p0.x = f2bf_fast(a0[0]); p0.y = f2bf_fast(a0[1]);
      p0.z = f2bf_fast(a0[2]); p0.w = f2bf_fast(a0[3]);
      p1.x = f2bf_fast(a1[0]); p1.y = f2bf_fast(a1[1]);
      p1.z = f2bf_fast(a1[2]); p1.w = f2bf_fast(a1[3]);
      *(ushort4*)(dst + (size_t)(row0 + lr) * 256 + ct * 16 + lg * 4) = p0;
      *(ushort4*)(dst + (size_t)(row0 + 16 + lr) * 256 + ct * 16 + lg * 4) = p1;
      if (sub == 0) __builtin_amdgcn_s_setprio(1);
    }
  }
}

// ---------------- output projection GEMM (LDS-staged weights) ----------------
// MODE 1: outf = resid + X@W.  MODE 2: scatter-add into h (float4 RMW).
// 8 rounds of 16KB pairs, __syncthreads. T5 setprio around MFMA clusters.
template<int MODE>
__global__ __launch_bounds__(256) void gemm256_kernel(
    const unsigned short* __restrict__ X, const unsigned short* __restrict__ WF,
    const float* __restrict__ resid, float* __restrict__ outf, int row_base) {
  __shared__ __align__(16) unsigned short Wbuf[2][8192];
  int tid = threadIdx.x, wv = tid >> 6, lane = tid & 63, lr = lane & 15, lg = lane >> 4;
  int row0 = blockIdx.x * 128 + wv * 32;
  short8 afrag[2][8];
  size_t rb[2];
  #pragma unroll
  for (int rt = 0; rt < 2; ++rt) {
    int row = row0 + rt * 16 + lr;
    #pragma unroll
    for (int ks = 0; ks < 8; ++ks)
      afrag[rt][ks] = *(const short8*)(X + (size_t)row * 256 + ks * 32 + lg * 8);
    if (MODE == 1) {
      rb[rt] = (size_t)row * 256;
    } else {
      int gr = row_base + row;
      int b = gr / 11776; int rem = gr - b * 11776;
      int j = rem >> 8, n = rem & 255;
      rb[rt] = (((size_t)((b << 8) + n) << 8) + act_t(j)) * 256;
    }
  }
  #pragma unroll
  for (int i = 0; i < 4; ++i) {
    int s = wv * 4 + i;
    load_lds16(WF + (size_t)s * 512 + lane * 8, &Wbuf[0][s * 512]);
  }
  f32x4 zero = {0.f, 0.f, 0.f, 0.f};
  for (int r = 0; r < 8; ++r) {
    __syncthreads();
    if (r < 7) {
      #pragma unroll
      for (int i = 0; i < 4; ++i) {
        int s = wv * 4 + i;
        load_lds16(WF + (size_t)(r + 1) * 8192 + s * 512 + lane * 8,
                   &Wbuf[(r + 1) & 1][s * 512]);
      }
    }
    __syncthreads();
    #pragma unroll
    for (int sub = 0; sub < 2; ++sub) {
      int t = r * 2 + sub;
      const unsigned short* Ws = &Wbuf[r & 1][sub * 4096];
      f32x4 a0 = zero, a1 = zero;
      __builtin_amdgcn_s_setprio(1);
      #pragma unroll
      for (int ks = 0; ks < 8; ++ks) {
        short8 bw = *(const short8*)&Ws[ks * 512 + lane * 8];
        a0 = __builtin_amdgcn_mfma_f32_16x16x32_bf16(bw, afrag[0][ks], a0, 0, 0, 0);
        a1 = __builtin_amdgcn_mfma_f32_16x16x32_bf16(bw, afrag[1][ks], a1, 0, 0, 0);
      }
      __builtin_amdgcn_s_setprio(0);
      int col = t * 16 + lg * 4;
      if (MODE == 1) {
        float4 r0 = *(const float4*)(resid + rb[0] + col);
        float4 r1 = *(const float4*)(resid + rb[1] + col);
        float4 o0, o1;
        o0.x = r0.x + a0[0]; o0.y = r0.y + a0[1]; o0.z = r0.z + a0[2]; o0.w = r0.w + a0[3];
        o1.x = r1.x + a1[0]; o1.y = r1.y + a1[1]; o1.z = r1.z + a1[2]; o1.w = r1.w + a1[3];
        *(float4*)(outf + rb[0] + col) = o0;
        *(float4*)(outf + rb[1] + col) = o1;
      } else {
        float4 c0 = *(const float4*)(outf + rb[0] + col);
        float4 c1 = *(const float4*)(outf + rb[1] + col);
        c0.x += a0[0]; c0.y += a0[1]; c0.z += a0[2]; c0.w += a0[3];
        c1.x += a1[0]; c1.y += a1[1]; c1.z += a1[2]; c1.w += a1[3];
        *(float4*)(outf + rb[0] + col) = c0;
        *(float4*)(outf + rb[1] + col) = c1;
      }
    }
  }
}

// ---------------- attention: one block per (head, seq); seq len 256, hdim 32 ----------------
// Coalesced staging: lane->(row=tid>>2, chunk=tid&3) => 64B-contiguous reads.
// Swapped QK^T; softmax reduce = 2 shfl_xor; swapped PV; vectorized O store.
// T5: setprio(1) around the MFMA clusters (R18: -63us, inter-block diversity).
template<int MASKED>
__global__ __launch_bounds__(256) void attn_kernel(
    const unsigned short* __restrict__ Q, const unsigned short* __restrict__ K,
    const unsigned short* __restrict__ V, unsigned short* __restrict__ O,
    const int* __restrict__ mask, int seq_base) {
  __shared__ unsigned short Ksh[256][40];    // padded
  __shared__ unsigned short Vtsh[32][264];   // V transposed [d][key]
  __shared__ unsigned short Psh[4][16][264]; // per-wave P: [qrow][key]
  int head = blockIdx.x, seq = blockIdx.y;
  int hc = head * 32;
  size_t sb = (size_t)seq * 65536;
  int tid = threadIdx.x;
  {
    int c = tid & 3, rbase = tid >> 2;
    #pragma unroll
    for (int i = 0; i < 4; ++i) {
      int r = rbase + i * 64;
      *(short8*)&Ksh[r][c * 8] = *(const short8*)(K + sb + (size_t)r * 256 + hc + c * 8);
      short8 vv = *(const short8*)(V + sb + (size_t)r * 256 + hc + c * 8);
      #pragma unroll
      for (int e = 0; e < 8; ++e) Vtsh[c * 8 + e][r] = (unsigned short)vv[e];
    }
  }
  __syncthreads();
  int wv = tid >> 6, lane = tid & 63, lr = lane & 15, lg = lane >> 4;
  const float scale = 0.17677669529663687f;  // 1/sqrt(32)
  int mb = 0;
  if (MASKED) mb = (seq_base + seq) / TP;
  f32x4 zero = {0.f, 0.f, 0.f, 0.f};
  for (int rt = 0; rt < 4; ++rt) {
    int row0 = wv * 64 + rt * 16;
    short8 aq = *(const short8*)(Q + sb + (size_t)(row0 + lr) * 256 + hc + lg * 8);
    f32x4 s[16];
    __builtin_amdgcn_s_setprio(1);
    #pragma unroll
    for (int ct = 0; ct < 16; ++ct) {
      short8 kb = *(const short8*)&Ksh[ct * 16 + lr][lg * 8];
      s[ct] = __builtin_amdgcn_mfma_f32_16x16x32_bf16(kb, aq, zero, 0, 0, 0);
    }
    __builtin_amdgcn_s_setprio(0);
    // s[ct][r] = S[qrow=lr][key = ct*16 + lg*4 + r]
    #pragma unroll
    for (int ct = 0; ct < 16; ++ct) {
      if (MASKED) {
        const int4 m4 = *(const int4*)(mask + mb * 256 + ct * 16 + lg * 4);
        s[ct][0] = m4.x ? s[ct][0] * scale : -1e9f;
        s[ct][1] = m4.y ? s[ct][1] * scale : -1e9f;
        s[ct][2] = m4.z ? s[ct][2] * scale : -1e9f;
        s[ct][3] = m4.w ? s[ct][3] * scale : -1e9f;
      } else {
        #pragma unroll
        for (int r = 0; r < 4; ++r) s[ct][r] *= scale;
      }
    }
    float mx = -3e38f;
    #pragma unroll
    for (int ct = 0; ct < 16; ++ct)
      #pragma unroll
      for (int r = 0; r < 4; ++r) mx = fmaxf(mx, s[ct][r]);
    mx = fmaxf(mx, __shfl_xor(mx, 16, 64));
    mx = fmaxf(mx, __shfl_xor(mx, 32, 64));
    float sum = 0.f;
    #pragma unroll
    for (int ct = 0; ct < 16; ++ct)
      #pragma unroll
      for (int r = 0; r < 4; ++r) {
        float p = __expf(s[ct][r] - mx);
        s[ct][r] = p; sum += p;
      }
    sum += __shfl_xor(sum, 16, 64);
    sum += __shfl_xor(sum, 32, 64);
    float inv = fast_rcp(sum);
    #pragma unroll
    for (int ct = 0; ct < 16; ++ct) {
      ushort4 pk;
      pk.x = f2bf_fast(s[ct][0] * inv); pk.y = f2bf_fast(s[ct][1] * inv);
      pk.z = f2bf_fast(s[ct][2] * inv); pk.w = f2bf_fast(s[ct][3] * inv);
      *(ushort4*)&Psh[wv][lr][ct * 16 + lg * 4] = pk;
    }
    f32x4 o[2] = {zero, zero};
    __builtin_amdgcn_s_setprio(1);
    #pragma unroll
    for (int ks = 0; ks < 8; ++ks) {
      short8 pa = *(const short8*)&Psh[wv][lr][ks * 32 + lg * 8];
      #pragma unroll
      for (int c2 = 0; c2 < 2; ++c2) {
        short8 vbf = *(const short8*)&Vtsh[c2 * 16 + lr][ks * 32 + lg * 8];
        o[c2] = __builtin_amdgcn_mfma_f32_16x16x32_bf16(vbf, pa, o[c2], 0, 0, 0);
      }
    }
    __builtin_amdgcn_s_setprio(0);
    // o[c2][r] = O[qrow=lr][d = c2*16 + lg*4 + r]
    #pragma unroll
    for (int c2 = 0; c2 < 2; ++c2) {
      ushort4 ok;
      ok.x = f2bf_fast(o[c2][0]); ok.y = f2bf_fast(o[c2][1]);
      ok.z = f2bf_fast(o[c2][2]); ok.w = f2bf_fast(o[c2][3]);
      *(ushort4*)(O + sb + (size_t)(row0 + lr) * 256 + hc + c2 * 16 + lg * 4) = ok;
    }
  }
}

// ---------------- fused rms + FFN: 4 blocks/CU + T5 setprio ------------------
// 256 thr / 4 waves / 64 rows / 16 rows per wave. Single 32KB weight buffer,
// two barriers per chunk, 37KB LDS. Blocks drift across fc-chunks -> inter-
// block role diversity; MFMA-cluster priority lets compute-phase blocks
// preempt staging-phase blocks (same mechanism as attn R18).
__global__ __launch_bounds__(256, 4) void ffn_kernel(
    float* __restrict__ hio, const float* __restrict__ nw,
    const unsigned short* __restrict__ W1F, const unsigned short* __restrict__ W2F,
    const float* __restrict__ b1, const float* __restrict__ b2) {
  __shared__ __align__(16) unsigned short Wbuf[16384];  // W1s 0..8191 | W2s 8192..
  __shared__ __align__(16) unsigned short Psh[4][16][36];
  int tid = threadIdx.x;
  int wv = tid >> 6, lane = tid & 63, lr = lane & 15, lg = lane >> 4;
  int wrow = blockIdx.x * 64 + wv * 16;
  const float* rp = hio + (size_t)(wrow + lr) * 256;
  short8 xfrag[8];
  float ss = 0.f;
  #pragma unroll
  for (int ks = 0; ks < 8; ++ks) {
    float4 a = *(const float4*)(rp + ks * 32 + lg * 8);
    float4 b = *(const float4*)(rp + ks * 32 + lg * 8 + 4);
    ss += a.x * a.x + a.y * a.y + a.z * a.z + a.w * a.w;
    ss += b.x * b.x + b.y * b.y + b.z * b.z + b.w * b.w;
    short8 xf;
    xf[0] = (short)f2bf_fast(a.x); xf[1] = (short)f2bf_fast(a.y);
    xf[2] = (short)f2bf_fast(a.z); xf[3] = (short)f2bf_fast(a.w);
    xf[4] = (short)f2bf_fast(b.x); xf[5] = (short)f2bf_fast(b.y);
    xf[6] = (short)f2bf_fast(b.z); xf[7] = (short)f2bf_fast(b.w);
    xfrag[ks] = xf;
  }
  ss += __shfl_xor(ss, 16, 64);
  ss += __shfl_xor(ss, 32, 64);
  float sc = fast_rsq(ss * 0.00390625f + 1e-6f);
  #pragma unroll
  for (int ks = 0; ks < 8; ++ks) {
    float4 wa = *(const float4*)(nw + ks * 32 + lg * 8);
    float4 wb = *(const float4*)(nw + ks * 32 + lg * 8 + 4);
    short8 xf = xfrag[ks], af;
    af[0] = (short)f2bf_fast(bf2f(xf[0]) * sc * wa.x);
    af[1] = (short)f2bf_fast(bf2f(xf[1]) * sc * wa.y);
    af[2] = (short)f2bf_fast(bf2f(xf[2]) * sc * wa.z);
    af[3] = (short)f2bf_fast(bf2f(xf[3]) * sc * wa.w);
    af[4] = (short)f2bf_fast(bf2f(xf[4]) * sc * wb.x);
    af[5] = (short)f2bf_fast(bf2f(xf[5]) * sc * wb.y);
    af[6] = (short)f2bf_fast(bf2f(xf[6]) * sc * wb.z);
    af[7] = (short)f2bf_fast(bf2f(xf[7]) * sc * wb.w);
    xfrag[ks] = af;
  }
  f32x4 zero = {0.f, 0.f, 0.f, 0.f};
  f32x4 oacc[16];
  #pragma unroll
  for (int ct = 0; ct < 16; ++ct) oacc[ct] = zero;
  for (int fc = 0; fc < 32; ++fc) {
    __syncthreads();  // all waves done reading previous chunk
    #pragma unroll
    for (int i = 0; i < 8; ++i) {
      int s = wv * 8 + i;
      const unsigned short* srcp = (s < 16) ? (W1F + (size_t)fc * 8192 + s * 512)
                                            : (W2F + (size_t)fc * 8192 + (s - 16) * 512);
      load_lds16(srcp + lane * 8, &Wbuf[s * 512]);
    }
    __syncthreads();  // staging complete (vmcnt drain + barrier)
    const unsigned short* W1s = &Wbuf[0];
    const unsigned short* W2s = &Wbuf[8192];
    f32x4 hacc[2];
    hacc[0] = zero; hacc[1] = zero;
    __builtin_amdgcn_s_setprio(1);
    #pragma unroll
    for (int ks = 0; ks < 8; ++ks) {
      #pragma unroll
      for (int ct = 0; ct < 2; ++ct) {
        short8 w1f = *(const short8*)&W1s[(ct * 8 + ks) * 512 + lane * 8];
        // swapped: D[ff][xrow] -> lane holds 4 consecutive ff for xrow=lr
        hacc[ct] = __builtin_amdgcn_mfma_f32_16x16x32_bf16(w1f, xfrag[ks], hacc[ct], 0, 0, 0);
      }
    }
    __builtin_amdgcn_s_setprio(0);
    #pragma unroll
    for (int ct = 0; ct < 2; ++ct) {
      float4 bb = *(const float4*)(b1 + fc * 32 + ct * 16 + lg * 4);
      ushort4 pk;
      float hv = hacc[ct][0] + bb.x;
      pk.x = f2bf_fast(hv * fast_rcp(1.0f + __expf(-1.5957691216057308f * fmaf(0.044715f * hv, hv * hv, hv))));
      hv = hacc[ct][1] + bb.y;
      pk.y = f2bf_fast(hv * fast_rcp(1.0f + __expf(-1.5957691216057308f * fmaf(0.044715f * hv, hv * hv, hv))));
      hv = hacc[ct][2] + bb.z;
      pk.z = f2bf_fast(hv * fast_rcp(1.0f + __expf(-1.5957691216057308f * fmaf(0.044715f * hv, hv * hv, hv))));
      hv = hacc[ct][3] + bb.w;
      pk.w = f2bf_fast(hv * fast_rcp(1.0f + __expf(-1.5957691216057308f * fmaf(0.044715f * hv, hv * hv, hv))));
      *(ushort4*)&Psh[wv][lr][ct * 16 + lg * 4] = pk;  // [xrow=lr][ff]
    }
    short8 pa = *(const short8*)&Psh[wv][lr][lg * 8];
    __builtin_amdgcn_s_setprio(1);
    #pragma unroll
    for (int ct2 = 0; ct2 < 16; ++ct2) {
      short8 bw2 = *(const short8*)&W2s[ct2 * 512 + lane * 8];
      oacc[ct2] = __builtin_amdgcn_mfma_f32_16x16x32_bf16(bw2, pa, oacc[ct2], 0, 0, 0);
    }
    __builtin_amdgcn_s_setprio(0);
  }
  // epilogue: lane holds 4 consecutive out-cols for row = wrow + lr
  size_t rbase = (size_t)(wrow + lr) * 256;
  #pragma unroll
  for (int ct2 = 0; ct2 < 16; ++ct2) {
    int col = ct2 * 16 + lg * 4;
    float4 bb2 = *(const float4*)(b2 + col);
    float4 cur = *(const float4*)(hio + rbase + col);
    cur.x += oacc[ct2][0] + bb2.x;
    cur.y += oacc[ct2][1] + bb2.y;
    cur.z += oacc[ct2][2] + bb2.z;
    cur.w += oacc[ct2][3] + bb2.w;
    *(float4*)(hio + rbase + col) = cur;
  }
}

extern "C" void kernel_launch(void* const* d_in, const int* in_sizes, int n_in,
                              void* d_out, int out_size, void* d_ws, size_t ws_size,
                              hipStream_t stream) {
  (void)in_sizes; (void)n_in; (void)out_size;
  const float* h   = (const float*)d_in[0];
  const int* smask = (const int*)d_in[1];
  const float* ntw = (const float*)d_in[2];
  const float* nsw = (const float*)d_in[3];
  const float* nfw = (const float*)d_in[4];
  const float* wq_t = (const float*)d_in[5];
  const float* wk_t = (const float*)d_in[6];
  const float* wv_t = (const float*)d_in[7];
  const float* wo_t = (const float*)d_in[8];
  const float* wq_s = (const float*)d_in[9];
  const float* wk_s = (const float*)d_in[10];
  const float* wv_s = (const float*)d_in[11];
  const float* wo_s = (const float*)d_in[12];
  const float* w1  = (const float*)d_in[13];
  const float* b1  = (const float*)d_in[14];
  const float* w2  = (const float*)d_in[15];
  const float* b2  = (const float*)d_in[16];
  float* out = (float*)d_out;
  unsigned short* pool = (unsigned short*)d_ws;

  unsigned short* WQKVtF = pool;                 // tiles 0..47
  unsigned short* WOtF   = pool + 196608;        // tiles 48..63
  unsigned short* WQKVsF = pool + 262144;        // tiles 64..111
  unsigned short* WOsF   = pool + 458752;        // tiles 112..127
  unsigned short* W1F    = pool + 524288;
  unsigned short* W2F    = pool + 786432;

  size_t wbytes = 1048576ull * 2;
  size_t avail = (ws_size > wbytes) ? (ws_size - wbytes) : 0;
  long long scl = (long long)(avail / 524288ull);  // 4 buffers x 128KB per sequence
  int SC = scl < 1 ? 1 : (scl > 512 ? 512 : (int)scl);
  unsigned short* xnorm = pool + 1048576;  // attention output buffer
  unsigned short* qb = xnorm + (size_t)SC * 65536;
  unsigned short* kb = qb + (size_t)SC * 65536;
  unsigned short* vb = kb + (size_t)SC * 65536;

  convw_kernel<<<4096, 256, 0, stream>>>(wq_t, wk_t, wv_t, wo_t, wq_s, wk_s, wv_s,
                                         wo_s, w1, w2, pool);

  // ---- stage 1: time attention over (b,n) sequences (512 of them) ----
  for (int s0 = 0; s0 < 512; s0 += SC) {
    int ns = (512 - s0 < SC) ? (512 - s0) : SC;
    int rows = ns * 256;
    qkv_kernel<0><<<rows / 128, 256, 0, stream>>>(h + (size_t)s0 * 65536, ntw, WQKVtF,
                                                  qb, kb, vb, 0);
    attn_kernel<0><<<dim3(8, ns), 256, 0, stream>>>(qb, kb, vb, xnorm, nullptr, 0);
    gemm256_kernel<1><<<rows / 128, 256, 0, stream>>>(xnorm, WOtF,
        h + (size_t)s0 * 65536, out + (size_t)s0 * 65536, 0);
  }

  // ---- stage 2: stock attention over gathered active-t slices (92 sequences) ----
  int SC2 = SC < 92 ? SC : 92;
  for (int s0 = 0; s0 < 92; s0 += SC2) {
    int ns = (92 - s0 < SC2) ? (92 - s0) : SC2;
    int rows = ns * 256;
    qkv_kernel<1><<<rows / 128, 256, 0, stream>>>(out, nsw, WQKVsF, qb, kb, vb, s0 * 256);
    attn_kernel<1><<<dim3(8, ns), 256, 0, stream>>>(qb, kb, vb, xnorm, smask, s0);
    gemm256_kernel<2><<<rows / 128, 256, 0, stream>>>(xnorm, WOsF, nullptr, out, s0 * 256);
  }

  // ---- stage 3: fused rms + FFN (single dispatch, 2048 blocks x 256 threads) ----
  ffn_kernel<<<2048, 256, 0, stream>>>(out, nfw, W1F, W2F, b1, b2);
}

// Round 21
// 623.423 us; speedup vs baseline: 1.1411x; 1.0006x over previous
//
#include <hip/hip_runtime.h>
#include <hip/hip_bf16.h>

typedef __attribute__((ext_vector_type(8))) short short8;
typedef __attribute__((ext_vector_type(4))) float f32x4;

#define TP 46  // active time steps: 30 strided + 16 dense

// raw barrier + counted vmcnt (T3/T4): never drain vmcnt to 0 in a steady loop
#define SBAR() asm volatile("s_barrier" ::: "memory")
#define VMCNT4() asm volatile("s_waitcnt vmcnt(4)" ::: "memory")
#define VMCNT0() asm volatile("s_waitcnt vmcnt(0)" ::: "memory")

__device__ __forceinline__ unsigned short f2bf(float f) {  // RNE (weights, one-time)
  unsigned int u = __float_as_uint(f);
  u = (u + 0x7fff + ((u >> 16) & 1)) >> 16;
  return (unsigned short)u;
}
__device__ __forceinline__ unsigned short f2bf_fast(float f) {
  return (unsigned short)((__float_as_uint(f) + 0x8000u) >> 16);
}
__device__ __forceinline__ float bf2f(short u) {
  return __uint_as_float((unsigned)(unsigned short)u << 16);
}
__device__ __forceinline__ float fast_rcp(float x) {
#if __has_builtin(__builtin_amdgcn_rcpf)
  return __builtin_amdgcn_rcpf(x);
#else
  return 1.0f / x;
#endif
}
__device__ __forceinline__ float fast_rsq(float x) {
#if __has_builtin(__builtin_amdgcn_rsqf)
  return __builtin_amdgcn_rsqf(x);
#else
  return rsqrtf(x);
#endif
}

__device__ __forceinline__ int act_t(int j) { return j < 30 ? (j << 3) : (210 + j); }

// async 16B/lane global->LDS: lds base must be wave-uniform; HW writes lane i at base+i*16
__device__ __forceinline__ void load_lds16(const unsigned short* g, unsigned short* lds_base) {
#if __has_builtin(__builtin_amdgcn_global_load_lds)
  __builtin_amdgcn_global_load_lds(
      (const __attribute__((address_space(1))) unsigned int*)(unsigned long long)g,
      (__attribute__((address_space(3))) unsigned int*)(unsigned int)(unsigned long long)lds_base,
      16, 0, 0);
#else
  int lane = threadIdx.x & 63;
  *(short8*)(lds_base + lane * 8) = *(const short8*)g;
#endif
}

// ---------------- weight convert to fragment-ordered bf16 ----------------
// pool elems: 128 tiles of 4096 for QKV/O (frag-ordered A-operand for swapped
// mfma):  tiles 0..15 Wq_t, 16..31 Wk_t, 32..47 Wv_t, 48..63 Wo_t,
//         64..79 Wq_s, 80..95 Wk_s, 96..111 Wv_s, 112..127 Wo_s.
// tile off = tile*4096 + ks*512 + lane*8 + e -> w[(ks*32+lg*8+e)*256 + ct*16+lr]
// W1F 524288: ((fc*2+ct)*8+ks)*512+lane*8+e -> w1[(ks*32+lg*8+e)*1024 + fc*32+ct*16+lr]
// W2F 786432: (fc*16+ct2)*512+lane*8+e2     -> w2[(fc*32+lg*8+e2)*256 + ct2*16+lr]
__global__ __launch_bounds__(256) void convw_kernel(
    const float* __restrict__ wq_t, const float* __restrict__ wk_t,
    const float* __restrict__ wv_t, const float* __restrict__ wo_t,
    const float* __restrict__ wq_s, const float* __restrict__ wk_s,
    const float* __restrict__ wv_s, const float* __restrict__ wo_s,
    const float* __restrict__ w1, const float* __restrict__ w2,
    unsigned short* __restrict__ pool) {
  int idx = blockIdx.x * 256 + threadIdx.x;
  float v;
  if (idx < 524288) {
    int tile = idx >> 12, local = idx & 4095;
    int ks = local >> 9, q = local & 511;
    int l = q >> 3, e = q & 7;
    int lr = l & 15, lg = l >> 4;
    int ct = tile & 15, grp = tile >> 4;
    const float* s = (grp == 0) ? wq_t : (grp == 1) ? wk_t : (grp == 2) ? wv_t :
                     (grp == 3) ? wo_t : (grp == 4) ? wq_s : (grp == 5) ? wk_s :
                     (grp == 6) ? wv_s : wo_s;
    v = s[(size_t)(ks * 32 + lg * 8 + e) * 256 + ct * 16 + lr];
  } else if (idx < 786432) {
    int local = idx - 524288;
    int e = local & 7, t = local >> 3;
    int lane = t & 63, ks = (t >> 6) & 7, ct = (t >> 9) & 1, fc = t >> 10;
    int lr = lane & 15, lg = lane >> 4;
    v = w1[(size_t)(ks * 32 + lg * 8 + e) * 1024 + fc * 32 + ct * 16 + lr];
  } else {
    int local = idx - 786432;
    int e2 = local & 7, t = local >> 3;
    int lane = t & 63, ct2 = (t >> 6) & 15, fc = t >> 10;
    int lr = lane & 15, lg = lane >> 4;
    v = w2[(size_t)(fc * 32 + lg * 8 + e2) * 256 + ct2 * 16 + lr];
  }
  pool[idx] = f2bf(v);
}

// ---------------- fused rmsnorm + QKV projection (counted-vmcnt pipeline) ----
// 256 thr / 4 waves / 128 rows. rms in-register. 48 weight tiles consumed as
// 24 rounds of 16KB pairs, double-buffered; 2 raw barriers + vmcnt(4) per
// round. T5 setprio(1) around the MFMA cluster (inter-block role diversity).
template<int GATHER>
__global__ __launch_bounds__(256) void qkv_kernel(
    const float* __restrict__ src, const float* __restrict__ nw,
    const unsigned short* __restrict__ WF,  // 48 fragment-ordered tiles
    unsigned short* __restrict__ qb, unsigned short* __restrict__ kb,
    unsigned short* __restrict__ vb, int row_base) {
  __shared__ __align__(16) unsigned short Wbuf[2][8192];
  int tid = threadIdx.x, wv = tid >> 6, lane = tid & 63, lr = lane & 15, lg = lane >> 4;
  int row0 = blockIdx.x * 128 + wv * 32;
  short8 afrag[2][8];
  #pragma unroll
  for (int rt = 0; rt < 2; ++rt) {
    int lrow = row0 + rt * 16 + lr;
    const float* rp;
    if (GATHER) {
      int gr = row_base + lrow;
      int b = gr / 11776; int rem = gr - b * 11776;
      int j = rem >> 8, n = rem & 255;
      rp = src + (((size_t)((b << 8) + n) << 8) + act_t(j)) * 256;
    } else {
      rp = src + (size_t)lrow * 256;
    }
    float4 x[16];
    #pragma unroll
    for (int ks = 0; ks < 8; ++ks) {
      x[ks * 2]     = *(const float4*)(rp + ks * 32 + lg * 8);
      x[ks * 2 + 1] = *(const float4*)(rp + ks * 32 + lg * 8 + 4);
    }
    float ss = 0.f;
    #pragma unroll
    for (int i = 0; i < 16; ++i)
      ss += x[i].x * x[i].x + x[i].y * x[i].y + x[i].z * x[i].z + x[i].w * x[i].w;
    ss += __shfl_xor(ss, 16, 64);
    ss += __shfl_xor(ss, 32, 64);
    float sc = fast_rsq(ss * 0.00390625f + 1e-6f);
    #pragma unroll
    for (int ks = 0; ks < 8; ++ks) {
      float4 w0 = *(const float4*)(nw + ks * 32 + lg * 8);
      float4 w1_ = *(const float4*)(nw + ks * 32 + lg * 8 + 4);
      short8 af;
      af[0] = (short)f2bf_fast(x[ks * 2].x * sc * w0.x);
      af[1] = (short)f2bf_fast(x[ks * 2].y * sc * w0.y);
      af[2] = (short)f2bf_fast(x[ks * 2].z * sc * w0.z);
      af[3] = (short)f2bf_fast(x[ks * 2].w * sc * w0.w);
      af[4] = (short)f2bf_fast(x[ks * 2 + 1].x * sc * w1_.x);
      af[5] = (short)f2bf_fast(x[ks * 2 + 1].y * sc * w1_.y);
      af[6] = (short)f2bf_fast(x[ks * 2 + 1].z * sc * w1_.z);
      af[7] = (short)f2bf_fast(x[ks * 2 + 1].w * sc * w1_.w);
      afrag[rt][ks] = af;
    }
  }
  // stage pair 0 (16 x 1KB segments; each wave stages 4)
  #pragma unroll
  for (int i = 0; i < 4; ++i) {
    int s = wv * 4 + i;
    load_lds16(WF + (size_t)s * 512 + lane * 8, &Wbuf[0][s * 512]);
  }
  f32x4 zero = {0.f, 0.f, 0.f, 0.f};
  for (int r = 0; r < 24; ++r) {
    SBAR();  // B1: all waves done computing pair r-1 -> buf[(r+1)&1] reusable
    if (r < 23) {
      #pragma unroll
      for (int i = 0; i < 4; ++i) {
        int s = wv * 4 + i;
        load_lds16(WF + (size_t)(r + 1) * 8192 + s * 512 + lane * 8,
                   &Wbuf[(r + 1) & 1][s * 512]);
      }
      VMCNT4();  // pair r's 4 loads retired; r+1's 4 stay in flight
    } else {
      VMCNT0();
    }
    SBAR();  // B2: every wave has waited its vmcnt -> pair r fully in LDS
    __builtin_amdgcn_s_setprio(1);
    #pragma unroll
    for (int sub = 0; sub < 2; ++sub) {
      int t = r * 2 + sub;
      const unsigned short* Ws = &Wbuf[r & 1][sub * 4096];
      f32x4 a0 = zero, a1 = zero;
      #pragma unroll
      for (int ks = 0; ks < 8; ++ks) {
        short8 bw = *(const short8*)&Ws[ks * 512 + lane * 8];
        a0 = __builtin_amdgcn_mfma_f32_16x16x32_bf16(bw, afrag[0][ks], a0, 0, 0, 0);
        a1 = __builtin_amdgcn_mfma_f32_16x16x32_bf16(bw, afrag[1][ks], a1, 0, 0, 0);
      }
      __builtin_amdgcn_s_setprio(0);
      int m = t >> 4, ct = t & 15;
      unsigned short* dst = (m == 0) ? qb : (m == 1) ? kb : vb;
      ushort4 p0, p1;
      p0.x = f2bf_fast(a0[0]); p0.y = f2bf_fast(a0[1]);
      p0.z = f2bf_fast(a0[2]); p0.w = f2bf_fast(a0[3]);
      p1.x = f2bf_fast(a1[0]); p1.y = f2bf_fast(a1[1]);
      p1.z = f2bf_fast(a1[2]); p1.w = f2bf_fast(a1[3]);
      *(ushort4*)(dst + (size_t)(row0 + lr) * 256 + ct * 16 + lg * 4) = p0;
      *(ushort4*)(dst + (size_t)(row0 + 16 + lr) * 256 + ct * 16 + lg * 4) = p1;
      if (sub == 0) __builtin_amdgcn_s_setprio(1);
    }
  }
}

// ---------------- output projection GEMM (LDS-staged weights) ----------------
// MODE 1: outf = resid + X@W.  MODE 2: scatter-add into h (float4 RMW).
// 8 rounds of 16KB pairs, __syncthreads. T5 setprio(1) around MFMA clusters.
template<int MODE>
__global__ __launch_bounds__(256) void gemm256_kernel(
    const unsigned short* __restrict__ X, const unsigned short* __restrict__ WF,
    const float* __restrict__ resid, float* __restrict__ outf, int row_base) {
  __shared__ __align__(16) unsigned short Wbuf[2][8192];
  int tid = threadIdx.x, wv = tid >> 6, lane = tid & 63, lr = lane & 15, lg = lane >> 4;
  int row0 = blockIdx.x * 128 + wv * 32;
  short8 afrag[2][8];
  size_t rb[2];
  #pragma unroll
  for (int rt = 0; rt < 2; ++rt) {
    int row = row0 + rt * 16 + lr;
    #pragma unroll
    for (int ks = 0; ks < 8; ++ks)
      afrag[rt][ks] = *(const short8*)(X + (size_t)row * 256 + ks * 32 + lg * 8);
    if (MODE == 1) {
      rb[rt] = (size_t)row * 256;
    } else {
      int gr = row_base + row;
      int b = gr / 11776; int rem = gr - b * 11776;
      int j = rem >> 8, n = rem & 255;
      rb[rt] = (((size_t)((b << 8) + n) << 8) + act_t(j)) * 256;
    }
  }
  #pragma unroll
  for (int i = 0; i < 4; ++i) {
    int s = wv * 4 + i;
    load_lds16(WF + (size_t)s * 512 + lane * 8, &Wbuf[0][s * 512]);
  }
  f32x4 zero = {0.f, 0.f, 0.f, 0.f};
  for (int r = 0; r < 8; ++r) {
    __syncthreads();
    if (r < 7) {
      #pragma unroll
      for (int i = 0; i < 4; ++i) {
        int s = wv * 4 + i;
        load_lds16(WF + (size_t)(r + 1) * 8192 + s * 512 + lane * 8,
                   &Wbuf[(r + 1) & 1][s * 512]);
      }
    }
    __syncthreads();
    #pragma unroll
    for (int sub = 0; sub < 2; ++sub) {
      int t = r * 2 + sub;
      const unsigned short* Ws = &Wbuf[r & 1][sub * 4096];
      f32x4 a0 = zero, a1 = zero;
      __builtin_amdgcn_s_setprio(1);
      #pragma unroll
      for (int ks = 0; ks < 8; ++ks) {
        short8 bw = *(const short8*)&Ws[ks * 512 + lane * 8];
        a0 = __builtin_amdgcn_mfma_f32_16x16x32_bf16(bw, afrag[0][ks], a0, 0, 0, 0);
        a1 = __builtin_amdgcn_mfma_f32_16x16x32_bf16(bw, afrag[1][ks], a1, 0, 0, 0);
      }
      __builtin_amdgcn_s_setprio(0);
      int col = t * 16 + lg * 4;
      if (MODE == 1) {
        float4 r0 = *(const float4*)(resid + rb[0] + col);
        float4 r1 = *(const float4*)(resid + rb[1] + col);
        float4 o0, o1;
        o0.x = r0.x + a0[0]; o0.y = r0.y + a0[1]; o0.z = r0.z + a0[2]; o0.w = r0.w + a0[3];
        o1.x = r1.x + a1[0]; o1.y = r1.y + a1[1]; o1.z = r1.z + a1[2]; o1.w = r1.w + a1[3];
        *(float4*)(outf + rb[0] + col) = o0;
        *(float4*)(outf + rb[1] + col) = o1;
      } else {
        float4 c0 = *(const float4*)(outf + rb[0] + col);
        float4 c1 = *(const float4*)(outf + rb[1] + col);
        c0.x += a0[0]; c0.y += a0[1]; c0.z += a0[2]; c0.w += a0[3];
        c1.x += a1[0]; c1.y += a1[1]; c1.z += a1[2]; c1.w += a1[3];
        *(float4*)(outf + rb[0] + col) = c0;
        *(float4*)(outf + rb[1] + col) = c1;
      }
    }
  }
}

// ---------------- attention: one block per (head, seq); seq len 256, hdim 32 ----------------
// Coalesced staging: lane->(row=tid>>2, chunk=tid&3) => 64B-contiguous reads.
// Swapped QK^T; softmax reduce = 2 shfl_xor; swapped PV; vectorized O store.
// T5: setprio(2) around MFMA clusters — attn is the most latency-sensitive
// kernel (2 blocks/CU); priority 2 restores its edge over stage-GEMM MFMA
// bursts (prio 1) in graph-overlap windows.
template<int MASKED>
__global__ __launch_bounds__(256) void attn_kernel(
    const unsigned short* __restrict__ Q, const unsigned short* __restrict__ K,
    const unsigned short* __restrict__ V, unsigned short* __restrict__ O,
    const int* __restrict__ mask, int seq_base) {
  __shared__ unsigned short Ksh[256][40];    // padded
  __shared__ unsigned short Vtsh[32][264];   // V transposed [d][key]
  __shared__ unsigned short Psh[4][16][264]; // per-wave P: [qrow][key]
  int head = blockIdx.x, seq = blockIdx.y;
  int hc = head * 32;
  size_t sb = (size_t)seq * 65536;
  int tid = threadIdx.x;
  {
    int c = tid & 3, rbase = tid >> 2;
    #pragma unroll
    for (int i = 0; i < 4; ++i) {
      int r = rbase + i * 64;
      *(short8*)&Ksh[r][c * 8] = *(const short8*)(K + sb + (size_t)r * 256 + hc + c * 8);
      short8 vv = *(const short8*)(V + sb + (size_t)r * 256 + hc + c * 8);
      #pragma unroll
      for (int e = 0; e < 8; ++e) Vtsh[c * 8 + e][r] = (unsigned short)vv[e];
    }
  }
  __syncthreads();
  int wv = tid >> 6, lane = tid & 63, lr = lane & 15, lg = lane >> 4;
  const float scale = 0.17677669529663687f;  // 1/sqrt(32)
  int mb = 0;
  if (MASKED) mb = (seq_base + seq) / TP;
  f32x4 zero = {0.f, 0.f, 0.f, 0.f};
  for (int rt = 0; rt < 4; ++rt) {
    int row0 = wv * 64 + rt * 16;
    short8 aq = *(const short8*)(Q + sb + (size_t)(row0 + lr) * 256 + hc + lg * 8);
    f32x4 s[16];
    __builtin_amdgcn_s_setprio(2);
    #pragma unroll
    for (int ct = 0; ct < 16; ++ct) {
      short8 kb = *(const short8*)&Ksh[ct * 16 + lr][lg * 8];
      s[ct] = __builtin_amdgcn_mfma_f32_16x16x32_bf16(kb, aq, zero, 0, 0, 0);
    }
    __builtin_amdgcn_s_setprio(0);
    // s[ct][r] = S[qrow=lr][key = ct*16 + lg*4 + r]
    #pragma unroll
    for (int ct = 0; ct < 16; ++ct) {
      if (MASKED) {
        const int4 m4 = *(const int4*)(mask + mb * 256 + ct * 16 + lg * 4);
        s[ct][0] = m4.x ? s[ct][0] * scale : -1e9f;
        s[ct][1] = m4.y ? s[ct][1] * scale : -1e9f;
        s[ct][2] = m4.z ? s[ct][2] * scale : -1e9f;
        s[ct][3] = m4.w ? s[ct][3] * scale : -1e9f;
      } else {
        #pragma unroll
        for (int r = 0; r < 4; ++r) s[ct][r] *= scale;
      }
    }
    float mx = -3e38f;
    #pragma unroll
    for (int ct = 0; ct < 16; ++ct)
      #pragma unroll
      for (int r = 0; r < 4; ++r) mx = fmaxf(mx, s[ct][r]);
    mx = fmaxf(mx, __shfl_xor(mx, 16, 64));
    mx = fmaxf(mx, __shfl_xor(mx, 32, 64));
    float sum = 0.f;
    #pragma unroll
    for (int ct = 0; ct < 16; ++ct)
      #pragma unroll
      for (int r = 0; r < 4; ++r) {
        float p = __expf(s[ct][r] - mx);
        s[ct][r] = p; sum += p;
      }
    sum += __shfl_xor(sum, 16, 64);
    sum += __shfl_xor(sum, 32, 64);
    float inv = fast_rcp(sum);
    #pragma unroll
    for (int ct = 0; ct < 16; ++ct) {
      ushort4 pk;
      pk.x = f2bf_fast(s[ct][0] * inv); pk.y = f2bf_fast(s[ct][1] * inv);
      pk.z = f2bf_fast(s[ct][2] * inv); pk.w = f2bf_fast(s[ct][3] * inv);
      *(ushort4*)&Psh[wv][lr][ct * 16 + lg * 4] = pk;
    }
    f32x4 o[2] = {zero, zero};
    __builtin_amdgcn_s_setprio(2);
    #pragma unroll
    for (int ks = 0; ks < 8; ++ks) {
      short8 pa = *(const short8*)&Psh[wv][lr][ks * 32 + lg * 8];
      #pragma unroll
      for (int c2 = 0; c2 < 2; ++c2) {
        short8 vbf = *(const short8*)&Vtsh[c2 * 16 + lr][ks * 32 + lg * 8];
        o[c2] = __builtin_amdgcn_mfma_f32_16x16x32_bf16(vbf, pa, o[c2], 0, 0, 0);
      }
    }
    __builtin_amdgcn_s_setprio(0);
    // o[c2][r] = O[qrow=lr][d = c2*16 + lg*4 + r]
    #pragma unroll
    for (int c2 = 0; c2 < 2; ++c2) {
      ushort4 ok;
      ok.x = f2bf_fast(o[c2][0]); ok.y = f2bf_fast(o[c2][1]);
      ok.z = f2bf_fast(o[c2][2]); ok.w = f2bf_fast(o[c2][3]);
      *(ushort4*)(O + sb + (size_t)(row0 + lr) * 256 + hc + c2 * 16 + lg * 4) = ok;
    }
  }
}

// ---------------- fused rms + FFN: 4 blocks/CU + T5 setprio ------------------
// 256 thr / 4 waves / 64 rows / 16 rows per wave. Single 32KB weight buffer,
// two barriers per chunk, 37KB LDS. Blocks drift across fc-chunks -> inter-
// block role diversity; MFMA-cluster priority (1) lets compute-phase blocks
// preempt staging-phase blocks.
__global__ __launch_bounds__(256, 4) void ffn_kernel(
    float* __restrict__ hio, const float* __restrict__ nw,
    const unsigned short* __restrict__ W1F, const unsigned short* __restrict__ W2F,
    const float* __restrict__ b1, const float* __restrict__ b2) {
  __shared__ __align__(16) unsigned short Wbuf[16384];  // W1s 0..8191 | W2s 8192..
  __shared__ __align__(16) unsigned short Psh[4][16][36];
  int tid = threadIdx.x;
  int wv = tid >> 6, lane = tid & 63, lr = lane & 15, lg = lane >> 4;
  int wrow = blockIdx.x * 64 + wv * 16;
  const float* rp = hio + (size_t)(wrow + lr) * 256;
  short8 xfrag[8];
  float ss = 0.f;
  #pragma unroll
  for (int ks = 0; ks < 8; ++ks) {
    float4 a = *(const float4*)(rp + ks * 32 + lg * 8);
    float4 b = *(const float4*)(rp + ks * 32 + lg * 8 + 4);
    ss += a.x * a.x + a.y * a.y + a.z * a.z + a.w * a.w;
    ss += b.x * b.x + b.y * b.y + b.z * b.z + b.w * b.w;
    short8 xf;
    xf[0] = (short)f2bf_fast(a.x); xf[1] = (short)f2bf_fast(a.y);
    xf[2] = (short)f2bf_fast(a.z); xf[3] = (short)f2bf_fast(a.w);
    xf[4] = (short)f2bf_fast(b.x); xf[5] = (short)f2bf_fast(b.y);
    xf[6] = (short)f2bf_fast(b.z); xf[7] = (short)f2bf_fast(b.w);
    xfrag[ks] = xf;
  }
  ss += __shfl_xor(ss, 16, 64);
  ss += __shfl_xor(ss, 32, 64);
  float sc = fast_rsq(ss * 0.00390625f + 1e-6f);
  #pragma unroll
  for (int ks = 0; ks < 8; ++ks) {
    float4 wa = *(const float4*)(nw + ks * 32 + lg * 8);
    float4 wb = *(const float4*)(nw + ks * 32 + lg * 8 + 4);
    short8 xf = xfrag[ks], af;
    af[0] = (short)f2bf_fast(bf2f(xf[0]) * sc * wa.x);
    af[1] = (short)f2bf_fast(bf2f(xf[1]) * sc * wa.y);
    af[2] = (short)f2bf_fast(bf2f(xf[2]) * sc * wa.z);
    af[3] = (short)f2bf_fast(bf2f(xf[3]) * sc * wa.w);
    af[4] = (short)f2bf_fast(bf2f(xf[4]) * sc * wb.x);
    af[5] = (short)f2bf_fast(bf2f(xf[5]) * sc * wb.y);
    af[6] = (short)f2bf_fast(bf2f(xf[6]) * sc * wb.z);
    af[7] = (short)f2bf_fast(bf2f(xf[7]) * sc * wb.w);
    xfrag[ks] = af;
  }
  f32x4 zero = {0.f, 0.f, 0.f, 0.f};
  f32x4 oacc[16];
  #pragma unroll
  for (int ct = 0; ct < 16; ++ct) oacc[ct] = zero;
  for (int fc = 0; fc < 32; ++fc) {
    __syncthreads();  // all waves done reading previous chunk
    #pragma unroll
    for (int i = 0; i < 8; ++i) {
      int s = wv * 8 + i;
      const unsigned short* srcp = (s < 16) ? (W1F + (size_t)fc * 8192 + s * 512)
                                            : (W2F + (size_t)fc * 8192 + (s - 16) * 512);
      load_lds16(srcp + lane * 8, &Wbuf[s * 512]);
    }
    __syncthreads();  // staging complete (vmcnt drain + barrier)
    const unsigned short* W1s = &Wbuf[0];
    const unsigned short* W2s = &Wbuf[8192];
    f32x4 hacc[2];
    hacc[0] = zero; hacc[1] = zero;
    __builtin_amdgcn_s_setprio(1);
    #pragma unroll
    for (int ks = 0; ks < 8; ++ks) {
      #pragma unroll
      for (int ct = 0; ct < 2; ++ct) {
        short8 w1f = *(const short8*)&W1s[(ct * 8 + ks) * 512 + lane * 8];
        // swapped: D[ff][xrow] -> lane holds 4 consecutive ff for xrow=lr
        hacc[ct] = __builtin_amdgcn_mfma_f32_16x16x32_bf16(w1f, xfrag[ks], hacc[ct], 0, 0, 0);
      }
    }
    __builtin_amdgcn_s_setprio(0);
    #pragma unroll
    for (int ct = 0; ct < 2; ++ct) {
      float4 bb = *(const float4*)(b1 + fc * 32 + ct * 16 + lg * 4);
      ushort4 pk;
      float hv = hacc[ct][0] + bb.x;
      pk.x = f2bf_fast(hv * fast_rcp(1.0f + __expf(-1.5957691216057308f * fmaf(0.044715f * hv, hv * hv, hv))));
      hv = hacc[ct][1] + bb.y;
      pk.y = f2bf_fast(hv * fast_rcp(1.0f + __expf(-1.5957691216057308f * fmaf(0.044715f * hv, hv * hv, hv))));
      hv = hacc[ct][2] + bb.z;
      pk.z = f2bf_fast(hv * fast_rcp(1.0f + __expf(-1.5957691216057308f * fmaf(0.044715f * hv, hv * hv, hv))));
      hv = hacc[ct][3] + bb.w;
      pk.w = f2bf_fast(hv * fast_rcp(1.0f + __expf(-1.5957691216057308f * fmaf(0.044715f * hv, hv * hv, hv))));
      *(ushort4*)&Psh[wv][lr][ct * 16 + lg * 4] = pk;  // [xrow=lr][ff]
    }
    short8 pa = *(const short8*)&Psh[wv][lr][lg * 8];
    __builtin_amdgcn_s_setprio(1);
    #pragma unroll
    for (int ct2 = 0; ct2 < 16; ++ct2) {
      short8 bw2 = *(const short8*)&W2s[ct2 * 512 + lane * 8];
      oacc[ct2] = __builtin_amdgcn_mfma_f32_16x16x32_bf16(bw2, pa, oacc[ct2], 0, 0, 0);
    }
    __builtin_amdgcn_s_setprio(0);
  }
  // epilogue: lane holds 4 consecutive out-cols for row = wrow + lr
  size_t rbase = (size_t)(wrow + lr) * 256;
  #pragma unroll
  for (int ct2 = 0; ct2 < 16; ++ct2) {
    int col = ct2 * 16 + lg * 4;
    float4 bb2 = *(const float4*)(b2 + col);
    float4 cur = *(const float4*)(hio + rbase + col);
    cur.x += oacc[ct2][0] + bb2.x;
    cur.y += oacc[ct2][1] + bb2.y;
    cur.z += oacc[ct2][2] + bb2.z;
    cur.w += oacc[ct2][3] + bb2.w;
    *(float4*)(hio + rbase + col) = cur;
  }
}

extern "C" void kernel_launch(void* const* d_in, const int* in_sizes, int n_in,
                              void* d_out, int out_size, void* d_ws, size_t ws_size,
                              hipStream_t stream) {
  (void)in_sizes; (void)n_in; (void)out_size;
  const float* h   = (const float*)d_in[0];
  const int* smask = (const int*)d_in[1];
  const float* ntw = (const float*)d_in[2];
  const float* nsw = (const float*)d_in[3];
  const float* nfw = (const float*)d_in[4];
  const float* wq_t = (const float*)d_in[5];
  const float* wk_t = (const float*)d_in[6];
  const float* wv_t = (const float*)d_in[7];
  const float* wo_t = (const float*)d_in[8];
  const float* wq_s = (const float*)d_in[9];
  const float* wk_s = (const float*)d_in[10];
  const float* wv_s = (const float*)d_in[11];
  const float* wo_s = (const float*)d_in[12];
  const float* w1  = (const float*)d_in[13];
  const float* b1  = (const float*)d_in[14];
  const float* w2  = (const float*)d_in[15];
  const float* b2  = (const float*)d_in[16];
  float* out = (float*)d_out;
  unsigned short* pool = (unsigned short*)d_ws;

  unsigned short* WQKVtF = pool;                 // tiles 0..47
  unsigned short* WOtF   = pool + 196608;        // tiles 48..63
  unsigned short* WQKVsF = pool + 262144;        // tiles 64..111
  unsigned short* WOsF   = pool + 458752;        // tiles 112..127
  unsigned short* W1F    = pool + 524288;
  unsigned short* W2F    = pool + 786432;

  size_t wbytes = 1048576ull * 2;
  size_t avail = (ws_size > wbytes) ? (ws_size - wbytes) : 0;
  long long scl = (long long)(avail / 524288ull);  // 4 buffers x 128KB per sequence
  int SC = scl < 1 ? 1 : (scl > 512 ? 512 : (int)scl);
  unsigned short* xnorm = pool + 1048576;  // attention output buffer
  unsigned short* qb = xnorm + (size_t)SC * 65536;
  unsigned short* kb = qb + (size_t)SC * 65536;
  unsigned short* vb = kb + (size_t)SC * 65536;

  convw_kernel<<<4096, 256, 0, stream>>>(wq_t, wk_t, wv_t, wo_t, wq_s, wk_s, wv_s,
                                         wo_s, w1, w2, pool);

  // ---- stage 1: time attention over (b,n) sequences (512 of them) ----
  for (int s0 = 0; s0 < 512; s0 += SC) {
    int ns = (512 - s0 < SC) ? (512 - s0) : SC;
    int rows = ns * 256;
    qkv_kernel<0><<<rows / 128, 256, 0, stream>>>(h + (size_t)s0 * 65536, ntw, WQKVtF,
                                                  qb, kb, vb, 0);
    attn_kernel<0><<<dim3(8, ns), 256, 0, stream>>>(qb, kb, vb, xnorm, nullptr, 0);
    gemm256_kernel<1><<<rows / 128, 256, 0, stream>>>(xnorm, WOtF,
        h + (size_t)s0 * 65536, out + (size_t)s0 * 65536, 0);
  }

  // ---- stage 2: stock attention over gathered active-t slices (92 sequences) ----
  int SC2 = SC < 92 ? SC : 92;
  for (int s0 = 0; s0 < 92; s0 += SC2) {
    int ns = (92 - s0 < SC2) ? (92 - s0) : SC2;
    int rows = ns * 256;
    qkv_kernel<1><<<rows / 128, 256, 0, stream>>>(out, nsw, WQKVsF, qb, kb, vb, s0 * 256);
    attn_kernel<1><<<dim3(8, ns), 256, 0, stream>>>(qb, kb, vb, xnorm, smask, s0);
    gemm256_kernel<2><<<rows / 128, 256, 0, stream>>>(xnorm, WOsF, nullptr, out, s0 * 256);
  }

  // ---- stage 3: fused rms + FFN (single dispatch, 2048 blocks x 256 threads) ----
  ffn_kernel<<<2048, 256, 0, stream>>>(out, nfw, W1F, W2F, b1, b2);
}